// Round 1
// baseline (702.133 us; speedup 1.0000x reference)
//
#include <hip/hip_runtime.h>
#include <cstdint>
#include <cstddef>

// ---- problem constants ----
#define BQ   8
#define NP   512
#define GQ   16
#define PP   528      // NP + GQ
#define RT   4224     // BQ * PP
#define CC   91
#define FEATD 12544
#define REPD 1024
#define NH   512      // padded head output cols (455 used: 91 cls + 364 box)
#define NHU  455
#define BETA (1.0f/9.0f)

typedef __bf16 bf16x8 __attribute__((ext_vector_type(8)));
typedef float  f32x4  __attribute__((ext_vector_type(4)));

__device__ __forceinline__ unsigned short f2bf(float f) {
  unsigned int x = __float_as_uint(f);
  unsigned int r = (x + 0x7fffu + ((x >> 16) & 1u)) >> 16;
  return (unsigned short)r;
}

// ---- workspace layout (bytes) ----
constexpr size_t O_FEAT = 0;
constexpr size_t SZ_FEAT = (size_t)RT * FEATD * 2;          // bf16 features
constexpr size_t O_W1T  = O_FEAT + SZ_FEAT;
constexpr size_t SZ_W1T = (size_t)FEATD * REPD * 2;         // W1^T bf16 [1024][12544]
constexpr size_t O_W2T  = O_W1T + SZ_W1T;
constexpr size_t SZ_W2T = (size_t)REPD * REPD * 2;          // W2^T bf16 [1024][1024]
constexpr size_t O_WH   = O_W2T + SZ_W2T;
constexpr size_t SZ_WH  = (size_t)NH * REPD * 2;            // [Wcls|Wbox]^T bf16 [512][1024]
constexpr size_t O_BH   = O_WH + SZ_WH;
constexpr size_t SZ_BH  = (size_t)NH * 4;                   // fused head bias fp32
constexpr size_t O_X1   = O_BH + SZ_BH;
constexpr size_t SZ_X1  = (size_t)RT * REPD * 2;            // x1 bf16
constexpr size_t O_X2   = O_X1 + SZ_X1;
constexpr size_t O_HO   = O_X2 + SZ_X1;
constexpr size_t SZ_HO  = (size_t)RT * NH * 4;              // head out fp32 [4224][512]
constexpr size_t O_LAB  = O_HO + SZ_HO;                     // int labels [4224]
constexpr size_t O_TGT  = O_LAB + (size_t)RT * 4;           // fp32 targets [4224][4]
constexpr size_t O_NLL  = O_TGT + (size_t)RT * 16;
constexpr size_t O_VC   = O_NLL + (size_t)RT * 4;
constexpr size_t O_SL1  = O_VC + (size_t)RT * 4;

// ---- fp32 -> bf16 convert (vectorized, grid-stride) ----
__global__ void convert_bf16(const float* __restrict__ in, unsigned short* __restrict__ out, long n4) {
  long i = (long)blockIdx.x * blockDim.x + threadIdx.x;
  long stride = (long)gridDim.x * blockDim.x;
  for (; i < n4; i += stride) {
    float4 f = ((const float4*)in)[i];
    ushort4 u;
    u.x = f2bf(f.x); u.y = f2bf(f.y); u.z = f2bf(f.z); u.w = f2bf(f.w);
    ((ushort4*)out)[i] = u;
  }
}

// ---- tiled transpose + convert: in[K,N] fp32 -> out[(n+row_off)*out_ld + k] bf16 ----
__global__ void transpose_conv(const float* __restrict__ in, unsigned short* __restrict__ out,
                               int K, int N, int row_off, int out_ld) {
  __shared__ float t[32][33];
  int n0 = blockIdx.x * 32, k0 = blockIdx.y * 32;
  int tx = threadIdx.x, ty = threadIdx.y;
#pragma unroll
  for (int i = 0; i < 4; ++i) {
    int k = k0 + ty + i * 8, n = n0 + tx;
    if (k < K && n < N) t[ty + i * 8][tx] = in[(size_t)k * N + n];
  }
  __syncthreads();
#pragma unroll
  for (int i = 0; i < 4; ++i) {
    int n = n0 + ty + i * 8, k = k0 + tx;
    if (n < N && k < K) out[(size_t)(n + row_off) * out_ld + k] = f2bf(t[tx][ty + i * 8]);
  }
}

// ---- zero pad rows of fused head weight, build fused head bias ----
__global__ void head_init(unsigned short* __restrict__ Wh, float* __restrict__ bh,
                          const float* __restrict__ bcls, const float* __restrict__ bbox) {
  int idx = blockIdx.x * blockDim.x + threadIdx.x;
  if (idx < (NH - NHU) * REPD) Wh[(size_t)NHU * REPD + idx] = 0;
  if (idx < NH) bh[idx] = (idx < CC) ? bcls[idx] : (idx < NHU ? bbox[idx - CC] : 0.0f);
}

// ---- matcher + box encode ----
__global__ void matcher_kernel(const float* __restrict__ proposals,
                               const float* __restrict__ gt_boxes,
                               const int* __restrict__ gt_labels,
                               int* __restrict__ labels,
                               float* __restrict__ tgts) {
  int r = blockIdx.x * blockDim.x + threadIdx.x;
  if (r >= RT) return;
  int b = r / PP, p = r % PP;
  float x0, y0, x1, y1;
  if (p < NP) {
    const float* q = proposals + ((size_t)b * NP + p) * 4;
    x0 = q[0]; y0 = q[1]; x1 = q[2]; y1 = q[3];
  } else {
    const float* q = gt_boxes + ((size_t)b * GQ + (p - NP)) * 4;
    x0 = q[0]; y0 = q[1]; x1 = q[2]; y1 = q[3];
  }
  float ap = (x1 - x0) * (y1 - y0);
  float best = -1.0f; int bi = 0;
#pragma unroll
  for (int g = 0; g < GQ; ++g) {
    const float* gb = gt_boxes + ((size_t)b * GQ + g) * 4;
    float gx0 = gb[0], gy0 = gb[1], gx1 = gb[2], gy1 = gb[3];
    float ag = (gx1 - gx0) * (gy1 - gy0);
    float iw = fmaxf(fminf(gx1, x1) - fmaxf(gx0, x0), 0.0f);
    float ih = fmaxf(fminf(gy1, y1) - fmaxf(gy0, y0), 0.0f);
    float inter = iw * ih;
    float iou = inter / (ag + ap - inter);
    if (iou > best) { best = iou; bi = g; }   // strict > keeps first max (jnp.argmax)
  }
  int lab = gt_labels[b * GQ + bi];
  if (best < 0.5f) lab = 0;    // FG==BG==0.5 -> ignore band is empty
  labels[r] = lab;
  const float* gb = gt_boxes + ((size_t)b * GQ + bi) * 4;
  float ew = x1 - x0, eh = y1 - y0;
  float ex = x0 + 0.5f * ew, ey = y0 + 0.5f * eh;
  float gw = gb[2] - gb[0], gh = gb[3] - gb[1];
  float gx = gb[0] + 0.5f * gw, gy = gb[1] + 0.5f * gh;
  tgts[r * 4 + 0] = 10.0f * (gx - ex) / ew;
  tgts[r * 4 + 1] = 10.0f * (gy - ey) / eh;
  tgts[r * 4 + 2] = 5.0f * logf(gw / ew);
  tgts[r * 4 + 3] = 5.0f * logf(gh / eh);
}

// ---- bf16 MFMA GEMM: C[M,Nc] = A[M,K] * Bt[Nc,K]^T + bias, optional ReLU ----
// 128x128 block, BK=32, 256 threads = 4 waves in 2x2, each wave 4x4 tiles of 16x16x32.
// LDS rows padded to 40 bf16 (80 B): 16B-aligned b128 reads, worst 2-way bank conflict (free).
template <bool RELU, bool OUT_BF16>
__global__ __launch_bounds__(256, 2)
void gemm_bt(const unsigned short* __restrict__ A,
             const unsigned short* __restrict__ Bt,
             const float* __restrict__ bias,
             void* __restrict__ outp,
             int M, int Nc, int K) {
  constexpr int LD = 40;
  __shared__ unsigned short As[128 * LD];
  __shared__ unsigned short Bs[128 * LD];

  const int tid = threadIdx.x;
  const int m0 = blockIdx.y * 128;
  const int n0 = blockIdx.x * 128;
  const int w   = tid >> 6;
  const int L   = tid & 63;
  const int q   = L >> 4;        // k-quad: frag covers k = q*8 .. q*8+7
  const int l16 = L & 15;
  const int wr  = (w >> 1) * 64; // wave row offset in 128x128
  const int wc  = (w & 1) * 64;  // wave col offset

  // staging: 512 16B-chunks per matrix tile; thread does chunks tid and tid+256
  const int sr = tid >> 2;          // tile row 0..63
  const int sc = (tid & 3) * 8;     // k offset within BK

  const unsigned short* Ag0 = A  + (size_t)(m0 + sr) * K + sc;
  const unsigned short* Ag1 = Ag0 + (size_t)64 * K;
  const unsigned short* Bg0 = Bt + (size_t)(n0 + sr) * K + sc;
  const unsigned short* Bg1 = Bg0 + (size_t)64 * K;

  uint4 pa0 = *(const uint4*)Ag0;
  uint4 pa1 = *(const uint4*)Ag1;
  uint4 pb0 = *(const uint4*)Bg0;
  uint4 pb1 = *(const uint4*)Bg1;

  f32x4 acc[4][4] = {};

  const int nk = K >> 5;
  for (int kb = 0; kb < nk; ++kb) {
    *(uint4*)&As[(sr)      * LD + sc] = pa0;
    *(uint4*)&As[(sr + 64) * LD + sc] = pa1;
    *(uint4*)&Bs[(sr)      * LD + sc] = pb0;
    *(uint4*)&Bs[(sr + 64) * LD + sc] = pb1;
    __syncthreads();
    if (kb + 1 < nk) {   // register prefetch of next K-block overlaps MFMAs
      int ko = (kb + 1) * 32;
      pa0 = *(const uint4*)(Ag0 + ko);
      pa1 = *(const uint4*)(Ag1 + ko);
      pb0 = *(const uint4*)(Bg0 + ko);
      pb1 = *(const uint4*)(Bg1 + ko);
    }
    bf16x8 af[4], bfr[4];
#pragma unroll
    for (int i = 0; i < 4; ++i)
      af[i] = *(const bf16x8*)&As[(wr + i * 16 + l16) * LD + q * 8];
#pragma unroll
    for (int j = 0; j < 4; ++j)
      bfr[j] = *(const bf16x8*)&Bs[(wc + j * 16 + l16) * LD + q * 8];
#pragma unroll
    for (int i = 0; i < 4; ++i)
#pragma unroll
      for (int j = 0; j < 4; ++j)
        acc[i][j] = __builtin_amdgcn_mfma_f32_16x16x32_bf16(af[i], bfr[j], acc[i][j], 0, 0, 0);
    __syncthreads();
  }

  // epilogue: D[row=q*4+r][col=l16] per 16x16 tile  (verified m89/m91 layout)
#pragma unroll
  for (int i = 0; i < 4; ++i) {
    int rowb = m0 + wr + i * 16 + q * 4;
#pragma unroll
    for (int j = 0; j < 4; ++j) {
      int col = n0 + wc + j * 16 + l16;
      float bv = bias[col];
#pragma unroll
      for (int r = 0; r < 4; ++r) {
        float v = acc[i][j][r] + bv;
        if (RELU) v = fmaxf(v, 0.0f);
        size_t off = (size_t)(rowb + r) * Nc + col;
        if (OUT_BF16) ((unsigned short*)outp)[off] = f2bf(v);
        else          ((float*)outp)[off] = v;
      }
    }
  }
}

// ---- per-row loss: one wave per row ----
__global__ void loss_row(const float* __restrict__ head, const int* __restrict__ labels,
                         const float* __restrict__ tgts, float* __restrict__ nll_v,
                         float* __restrict__ vc_v, float* __restrict__ sl1_v) {
  int r = blockIdx.x;
  int l = threadIdx.x;
  const float* hg = head + (size_t)r * NH;
  float v1 = hg[l];                                    // cols 0..63
  float v2 = (l < CC - 64) ? hg[64 + l] : -3.4e38f;    // cols 64..90
  float m = fmaxf(v1, v2);
#pragma unroll
  for (int o = 32; o; o >>= 1) m = fmaxf(m, __shfl_xor(m, o));
  float e = __expf(v1 - m) + ((l < CC - 64) ? __expf(v2 - m) : 0.0f);
#pragma unroll
  for (int o = 32; o; o >>= 1) e += __shfl_xor(e, o);
  if (l == 0) {
    float lse = m + __logf(e);
    int lab = labels[r];
    int sl = lab < 0 ? 0 : (lab > CC - 1 ? CC - 1 : lab);
    float valid = (lab >= 0) ? 1.0f : 0.0f;
    nll_v[r] = (lse - hg[sl]) * valid;
    vc_v[r] = valid;
    float s = 0.0f;
#pragma unroll
    for (int d = 0; d < 4; ++d) {
      float pd = hg[CC + sl * 4 + d];
      float ad = fabsf(pd - tgts[r * 4 + d]);
      s += (ad < BETA) ? 0.5f * ad * ad / BETA : ad - 0.5f * BETA;
    }
    sl1_v[r] = (lab > 0) ? s : 0.0f;
  }
}

// ---- deterministic final reduce ----
__global__ void reduce_final(const float* __restrict__ nll_v, const float* __restrict__ vc_v,
                             const float* __restrict__ sl1_v, float* __restrict__ out) {
  __shared__ float s1[256], s2[256], s3[256];
  int t = threadIdx.x;
  float a = 0, b = 0, c = 0;
  for (int i = t; i < RT; i += 256) { a += nll_v[i]; b += vc_v[i]; c += sl1_v[i]; }
  s1[t] = a; s2[t] = b; s3[t] = c;
  __syncthreads();
  for (int o = 128; o; o >>= 1) {
    if (t < o) { s1[t] += s1[t + o]; s2[t] += s2[t + o]; s3[t] += s3[t + o]; }
    __syncthreads();
  }
  if (t == 0) {
    out[0] = s1[0] / fmaxf(s2[0], 1.0f);
    out[1] = s3[0] / (float)RT;
  }
}

extern "C" void kernel_launch(void* const* d_in, const int* in_sizes, int n_in,
                              void* d_out, int out_size, void* d_ws, size_t ws_size,
                              hipStream_t stream) {
  const float* proposals = (const float*)d_in[0];
  const float* gt_boxes  = (const float*)d_in[1];
  const float* features  = (const float*)d_in[2];
  const float* W1   = (const float*)d_in[3];
  const float* b1   = (const float*)d_in[4];
  const float* W2   = (const float*)d_in[5];
  const float* b2   = (const float*)d_in[6];
  const float* Wcls = (const float*)d_in[7];
  const float* bcls = (const float*)d_in[8];
  const float* Wbox = (const float*)d_in[9];
  const float* bbox = (const float*)d_in[10];
  const int* gt_labels = (const int*)d_in[11];
  float* out = (float*)d_out;

  char* ws = (char*)d_ws;
  unsigned short* feat_bf = (unsigned short*)(ws + O_FEAT);
  unsigned short* W1t  = (unsigned short*)(ws + O_W1T);
  unsigned short* W2t  = (unsigned short*)(ws + O_W2T);
  unsigned short* Wh   = (unsigned short*)(ws + O_WH);
  float* bh            = (float*)(ws + O_BH);
  unsigned short* x1   = (unsigned short*)(ws + O_X1);
  unsigned short* x2   = (unsigned short*)(ws + O_X2);
  float* head_out      = (float*)(ws + O_HO);
  int* labels          = (int*)(ws + O_LAB);
  float* tgts          = (float*)(ws + O_TGT);
  float* nll_v         = (float*)(ws + O_NLL);
  float* vc_v          = (float*)(ws + O_VC);
  float* sl1_v         = (float*)(ws + O_SL1);

  // 1. feature fp32 -> bf16
  convert_bf16<<<2048, 256, 0, stream>>>(features, feat_bf, (long)RT * FEATD / 4);
  // 2. weight transposes (to B^T layout) + fused head
  transpose_conv<<<dim3(REPD / 32, FEATD / 32), dim3(32, 8), 0, stream>>>(W1, W1t, FEATD, REPD, 0, FEATD);
  transpose_conv<<<dim3(REPD / 32, REPD / 32), dim3(32, 8), 0, stream>>>(W2, W2t, REPD, REPD, 0, REPD);
  transpose_conv<<<dim3((CC + 31) / 32, REPD / 32), dim3(32, 8), 0, stream>>>(Wcls, Wh, REPD, CC, 0, REPD);
  transpose_conv<<<dim3((4 * CC + 31) / 32, REPD / 32), dim3(32, 8), 0, stream>>>(Wbox, Wh, REPD, 4 * CC, CC, REPD);
  head_init<<<228, 256, 0, stream>>>(Wh, bh, bcls, bbox);
  // 3. matcher + encode
  matcher_kernel<<<(RT + 255) / 256, 256, 0, stream>>>(proposals, gt_boxes, gt_labels, labels, tgts);
  // 4. MLP + heads
  gemm_bt<true, true><<<dim3(REPD / 128, RT / 128), 256, 0, stream>>>(feat_bf, W1t, b1, x1, RT, REPD, FEATD);
  gemm_bt<true, true><<<dim3(REPD / 128, RT / 128), 256, 0, stream>>>(x1, W2t, b2, x2, RT, REPD, REPD);
  gemm_bt<false, false><<<dim3(NH / 128, RT / 128), 256, 0, stream>>>(x2, Wh, bh, head_out, RT, NH, REPD);
  // 5. losses
  loss_row<<<RT, 64, 0, stream>>>(head_out, labels, tgts, nll_v, vc_v, sl1_v);
  reduce_final<<<1, 256, 0, stream>>>(nll_v, vc_v, sl1_v, out);
}

// Round 2
// 637.761 us; speedup vs baseline: 1.1009x; 1.1009x over previous
//
#include <hip/hip_runtime.h>
#include <cstdint>
#include <cstddef>

// ---- problem constants ----
#define BQ   8
#define NP   512
#define GQ   16
#define PP   528      // NP + GQ
#define RT   4224     // BQ * PP
#define CC   91
#define FEATD 12544
#define REPD 1024
#define NH   512      // padded head output cols (455 used: 91 cls + 364 box)
#define NHU  455
#define BETA (1.0f/9.0f)

typedef __bf16 bf16x8 __attribute__((ext_vector_type(8)));
typedef float  f32x4  __attribute__((ext_vector_type(4)));

__device__ __forceinline__ unsigned short f2bf(float f) {
  unsigned int x = __float_as_uint(f);
  unsigned int r = (x + 0x7fffu + ((x >> 16) & 1u)) >> 16;
  return (unsigned short)r;
}

// async global->LDS DMA, 16 B per lane. LDS dst is wave-uniform base; HW
// writes lane L to base + L*16.
__device__ __forceinline__ void ld_lds16(const void* g, void* l) {
  __builtin_amdgcn_global_load_lds(
      (const __attribute__((address_space(1))) void*)g,
      (__attribute__((address_space(3))) void*)l, 16, 0, 0);
}

// ---- workspace layout (bytes) ----
constexpr size_t O_FEAT = 0;
constexpr size_t SZ_FEAT = (size_t)RT * FEATD * 2;          // bf16 features
constexpr size_t O_W1T  = O_FEAT + SZ_FEAT;
constexpr size_t SZ_W1T = (size_t)FEATD * REPD * 2;         // W1^T bf16 [1024][12544]
constexpr size_t O_W2T  = O_W1T + SZ_W1T;
constexpr size_t SZ_W2T = (size_t)REPD * REPD * 2;          // W2^T bf16 [1024][1024]
constexpr size_t O_WH   = O_W2T + SZ_W2T;
constexpr size_t SZ_WH  = (size_t)NH * REPD * 2;            // [Wcls|Wbox]^T bf16 [512][1024]
constexpr size_t O_BH   = O_WH + SZ_WH;
constexpr size_t SZ_BH  = (size_t)NH * 4;                   // fused head bias fp32
constexpr size_t O_X1   = O_BH + SZ_BH;
constexpr size_t SZ_X1  = (size_t)RT * REPD * 2;            // x1 bf16
constexpr size_t O_X2   = O_X1 + SZ_X1;
constexpr size_t O_HO   = O_X2 + SZ_X1;
constexpr size_t SZ_HO  = (size_t)RT * NH * 4;              // head out fp32 [4224][512]
constexpr size_t O_LAB  = O_HO + SZ_HO;                     // int labels [4224]
constexpr size_t O_TGT  = O_LAB + (size_t)RT * 4;           // fp32 targets [4224][4]
constexpr size_t O_NLL  = O_TGT + (size_t)RT * 16;
constexpr size_t O_VC   = O_NLL + (size_t)RT * 4;
constexpr size_t O_SL1  = O_VC + (size_t)RT * 4;
constexpr size_t O_PART = ((O_SL1 + (size_t)RT * 4) + 255) & ~(size_t)255;  // fp32 split-K partials
constexpr size_t SZ_P2  = (size_t)2 * RT * REPD * 4;        // 34.6 MB
constexpr size_t SZ_P4  = (size_t)4 * RT * REPD * 4;        // 69.2 MB

// ---- fp32 -> bf16 convert (vectorized, grid-stride) ----
__global__ void convert_bf16(const float* __restrict__ in, unsigned short* __restrict__ out, long n4) {
  long i = (long)blockIdx.x * blockDim.x + threadIdx.x;
  long stride = (long)gridDim.x * blockDim.x;
  for (; i < n4; i += stride) {
    float4 f = ((const float4*)in)[i];
    ushort4 u;
    u.x = f2bf(f.x); u.y = f2bf(f.y); u.z = f2bf(f.z); u.w = f2bf(f.w);
    ((ushort4*)out)[i] = u;
  }
}

// ---- tiled transpose + convert: in[K,N] fp32 -> out[(n+row_off)*out_ld + k] bf16 ----
__global__ void transpose_conv(const float* __restrict__ in, unsigned short* __restrict__ out,
                               int K, int N, int row_off, int out_ld) {
  __shared__ float t[32][33];
  int n0 = blockIdx.x * 32, k0 = blockIdx.y * 32;
  int tx = threadIdx.x, ty = threadIdx.y;
#pragma unroll
  for (int i = 0; i < 4; ++i) {
    int k = k0 + ty + i * 8, n = n0 + tx;
    if (k < K && n < N) t[ty + i * 8][tx] = in[(size_t)k * N + n];
  }
  __syncthreads();
#pragma unroll
  for (int i = 0; i < 4; ++i) {
    int n = n0 + ty + i * 8, k = k0 + tx;
    if (n < N && k < K) out[(size_t)(n + row_off) * out_ld + k] = f2bf(t[tx][ty + i * 8]);
  }
}

// ---- zero pad rows of fused head weight, build fused head bias ----
__global__ void head_init(unsigned short* __restrict__ Wh, float* __restrict__ bh,
                          const float* __restrict__ bcls, const float* __restrict__ bbox) {
  int idx = blockIdx.x * blockDim.x + threadIdx.x;
  if (idx < (NH - NHU) * REPD) Wh[(size_t)NHU * REPD + idx] = 0;
  if (idx < NH) bh[idx] = (idx < CC) ? bcls[idx] : (idx < NHU ? bbox[idx - CC] : 0.0f);
}

// ---- matcher + box encode ----
__global__ void matcher_kernel(const float* __restrict__ proposals,
                               const float* __restrict__ gt_boxes,
                               const int* __restrict__ gt_labels,
                               int* __restrict__ labels,
                               float* __restrict__ tgts) {
  int r = blockIdx.x * blockDim.x + threadIdx.x;
  if (r >= RT) return;
  int b = r / PP, p = r % PP;
  float x0, y0, x1, y1;
  if (p < NP) {
    const float* q = proposals + ((size_t)b * NP + p) * 4;
    x0 = q[0]; y0 = q[1]; x1 = q[2]; y1 = q[3];
  } else {
    const float* q = gt_boxes + ((size_t)b * GQ + (p - NP)) * 4;
    x0 = q[0]; y0 = q[1]; x1 = q[2]; y1 = q[3];
  }
  float ap = (x1 - x0) * (y1 - y0);
  float best = -1.0f; int bi = 0;
#pragma unroll
  for (int g = 0; g < GQ; ++g) {
    const float* gb = gt_boxes + ((size_t)b * GQ + g) * 4;
    float gx0 = gb[0], gy0 = gb[1], gx1 = gb[2], gy1 = gb[3];
    float ag = (gx1 - gx0) * (gy1 - gy0);
    float iw = fmaxf(fminf(gx1, x1) - fmaxf(gx0, x0), 0.0f);
    float ih = fmaxf(fminf(gy1, y1) - fmaxf(gy0, y0), 0.0f);
    float inter = iw * ih;
    float iou = inter / (ag + ap - inter);
    if (iou > best) { best = iou; bi = g; }   // strict > keeps first max (jnp.argmax)
  }
  int lab = gt_labels[b * GQ + bi];
  if (best < 0.5f) lab = 0;    // FG==BG==0.5 -> ignore band is empty
  labels[r] = lab;
  const float* gb = gt_boxes + ((size_t)b * GQ + bi) * 4;
  float ew = x1 - x0, eh = y1 - y0;
  float ex = x0 + 0.5f * ew, ey = y0 + 0.5f * eh;
  float gw = gb[2] - gb[0], gh = gb[3] - gb[1];
  float gx = gb[0] + 0.5f * gw, gy = gb[1] + 0.5f * gh;
  tgts[r * 4 + 0] = 10.0f * (gx - ex) / ew;
  tgts[r * 4 + 1] = 10.0f * (gy - ey) / eh;
  tgts[r * 4 + 2] = 5.0f * logf(gw / ew);
  tgts[r * 4 + 3] = 5.0f * logf(gh / eh);
}

// ---- bf16 MFMA GEMM, m97-style global_load_lds staging + split-K ----
// P[kz][M][Nc] += A[M, kz-slice] * Bt[Nc, kz-slice]^T
// 128x128 tile, BK=32, 256 thr = 4 waves (2x2 of 64x64), each wave 4x4 MFMA 16x16x32.
// LDS [row][32k] unpadded (global_load_lds lane-order requirement); 16-B chunk
// position XOR-swizzled with (row>>1)&3 -> ds_read_b128 is 2-way max (free).
__global__ __launch_bounds__(256, 4)
void gemm_lds(const unsigned short* __restrict__ A,
              const unsigned short* __restrict__ Bt,
              float* __restrict__ P,
              int M, int Nc, int K, int Kspl) {
  __shared__ unsigned short As[128 * 32];
  __shared__ unsigned short Bs[128 * 32];

  const int tid = threadIdx.x;
  const int m0 = blockIdx.y * 128;
  const int n0 = blockIdx.x * 128;
  const int kz = blockIdx.z;
  const int w   = tid >> 6;
  const int L   = tid & 63;
  const int q   = L >> 4;
  const int l16 = L & 15;
  const int wr  = (w >> 1) * 64;
  const int wc  = (w & 1) * 64;

  // staging: seg = 16 rows x 32 k = 1 KB. Wave w owns segs {2w, 2w+1} of each tile.
  // lane L lands at seg_base + L*16 B = row (L>>2), chunk (L&3). The global chunk
  // it must fetch is the swizzled one: c = (L&3) ^ ((row>>1)&3).
  const int s0 = w * 2;
  const int r0 = s0 * 16 + (L >> 2);           // tile-local row, first seg
  const int r1 = r0 + 16;                      // second seg
  const int k0off = ((L & 3) ^ ((r0 >> 1) & 3)) * 8;
  const int k1off = ((L & 3) ^ ((r1 >> 1) & 3)) * 8;
  const size_t kbase = (size_t)kz * Kspl;

  const unsigned short* Ag0 = A  + (size_t)(m0 + r0) * K + kbase + k0off;
  const unsigned short* Ag1 = A  + (size_t)(m0 + r1) * K + kbase + k1off;
  const unsigned short* Bg0 = Bt + (size_t)(n0 + r0) * K + kbase + k0off;
  const unsigned short* Bg1 = Bt + (size_t)(n0 + r1) * K + kbase + k1off;
  unsigned short* Al0 = &As[(s0)     * 512];   // wave-uniform LDS bases
  unsigned short* Al1 = &As[(s0 + 1) * 512];
  unsigned short* Bl0 = &Bs[(s0)     * 512];
  unsigned short* Bl1 = &Bs[(s0 + 1) * 512];

  // fragment LDS addresses (swizzle folded in), constant across K-loop
  const unsigned short* afp[4];
  const unsigned short* bfp[4];
#pragma unroll
  for (int i = 0; i < 4; ++i) {
    int ra = wr + i * 16 + l16;
    afp[i] = &As[ra * 32 + (q ^ ((ra >> 1) & 3)) * 8];
    int rb = wc + i * 16 + l16;
    bfp[i] = &Bs[rb * 32 + (q ^ ((rb >> 1) & 3)) * 8];
  }

  f32x4 acc[4][4] = {};
  const int nk = Kspl >> 5;
  for (int kb = 0; kb < nk; ++kb) {
    const int ko = kb * 32;
    ld_lds16(Ag0 + ko, Al0);
    ld_lds16(Ag1 + ko, Al1);
    ld_lds16(Bg0 + ko, Bl0);
    ld_lds16(Bg1 + ko, Bl1);
    __syncthreads();   // vmcnt(0) drain + barrier: tile staged
    bf16x8 af[4], bfr[4];
#pragma unroll
    for (int i = 0; i < 4; ++i) af[i]  = *(const bf16x8*)afp[i];
#pragma unroll
    for (int j = 0; j < 4; ++j) bfr[j] = *(const bf16x8*)bfp[j];
#pragma unroll
    for (int i = 0; i < 4; ++i)
#pragma unroll
      for (int j = 0; j < 4; ++j)
        acc[i][j] = __builtin_amdgcn_mfma_f32_16x16x32_bf16(af[i], bfr[j], acc[i][j], 0, 0, 0);
    __syncthreads();   // protect LDS from next iteration's DMA
  }

  // epilogue: D[row=q*4+r][col=l16] per 16x16 tile (verified layout) -> fp32 partials
  float* Pz = P + (size_t)kz * M * Nc;
#pragma unroll
  for (int i = 0; i < 4; ++i) {
    int rowb = m0 + wr + i * 16 + q * 4;
#pragma unroll
    for (int j = 0; j < 4; ++j) {
      int col = n0 + wc + j * 16 + l16;
#pragma unroll
      for (int r = 0; r < 4; ++r)
        Pz[(size_t)(rowb + r) * Nc + col] = acc[i][j][r];
    }
  }
}

// ---- split-K reduce + bias (+ReLU) (+bf16 cast) ----
template <int S, bool RELU, bool BF16OUT>
__global__ void reduce_split(const float* __restrict__ P, const float* __restrict__ bias,
                             void* __restrict__ outp, int M, int Nc) {
  const long MN4 = (long)M * Nc / 4;
  const int nc4 = Nc / 4;
  long i = (long)blockIdx.x * blockDim.x + threadIdx.x;
  long stride = (long)gridDim.x * blockDim.x;
  const float4* P4 = (const float4*)P;
  const float4* B4 = (const float4*)bias;
  for (; i < MN4; i += stride) {
    float4 v = P4[i];
#pragma unroll
    for (int s = 1; s < S; ++s) {
      float4 u = P4[s * MN4 + i];
      v.x += u.x; v.y += u.y; v.z += u.z; v.w += u.w;
    }
    float4 b = B4[i % nc4];
    v.x += b.x; v.y += b.y; v.z += b.z; v.w += b.w;
    if (RELU) {
      v.x = fmaxf(v.x, 0.f); v.y = fmaxf(v.y, 0.f);
      v.z = fmaxf(v.z, 0.f); v.w = fmaxf(v.w, 0.f);
    }
    if (BF16OUT) {
      ushort4 u; u.x = f2bf(v.x); u.y = f2bf(v.y); u.z = f2bf(v.z); u.w = f2bf(v.w);
      ((ushort4*)outp)[i] = u;
    } else {
      ((float4*)outp)[i] = v;
    }
  }
}

// ---- per-row loss: one wave per row ----
__global__ void loss_row(const float* __restrict__ head, const int* __restrict__ labels,
                         const float* __restrict__ tgts, float* __restrict__ nll_v,
                         float* __restrict__ vc_v, float* __restrict__ sl1_v) {
  int r = blockIdx.x;
  int l = threadIdx.x;
  const float* hg = head + (size_t)r * NH;
  float v1 = hg[l];
  float v2 = (l < CC - 64) ? hg[64 + l] : -3.4e38f;
  float m = fmaxf(v1, v2);
#pragma unroll
  for (int o = 32; o; o >>= 1) m = fmaxf(m, __shfl_xor(m, o));
  float e = __expf(v1 - m) + ((l < CC - 64) ? __expf(v2 - m) : 0.0f);
#pragma unroll
  for (int o = 32; o; o >>= 1) e += __shfl_xor(e, o);
  if (l == 0) {
    float lse = m + __logf(e);
    int lab = labels[r];
    int sl = lab < 0 ? 0 : (lab > CC - 1 ? CC - 1 : lab);
    float valid = (lab >= 0) ? 1.0f : 0.0f;
    nll_v[r] = (lse - hg[sl]) * valid;
    vc_v[r] = valid;
    float s = 0.0f;
#pragma unroll
    for (int d = 0; d < 4; ++d) {
      float pd = hg[CC + sl * 4 + d];
      float ad = fabsf(pd - tgts[r * 4 + d]);
      s += (ad < BETA) ? 0.5f * ad * ad / BETA : ad - 0.5f * BETA;
    }
    sl1_v[r] = (lab > 0) ? s : 0.0f;
  }
}

// ---- deterministic final reduce ----
__global__ void reduce_final(const float* __restrict__ nll_v, const float* __restrict__ vc_v,
                             const float* __restrict__ sl1_v, float* __restrict__ out) {
  __shared__ float s1[256], s2[256], s3[256];
  int t = threadIdx.x;
  float a = 0, b = 0, c = 0;
  for (int i = t; i < RT; i += 256) { a += nll_v[i]; b += vc_v[i]; c += sl1_v[i]; }
  s1[t] = a; s2[t] = b; s3[t] = c;
  __syncthreads();
  for (int o = 128; o; o >>= 1) {
    if (t < o) { s1[t] += s1[t + o]; s2[t] += s2[t + o]; s3[t] += s3[t + o]; }
    __syncthreads();
  }
  if (t == 0) {
    out[0] = s1[0] / fmaxf(s2[0], 1.0f);
    out[1] = s3[0] / (float)RT;
  }
}

extern "C" void kernel_launch(void* const* d_in, const int* in_sizes, int n_in,
                              void* d_out, int out_size, void* d_ws, size_t ws_size,
                              hipStream_t stream) {
  const float* proposals = (const float*)d_in[0];
  const float* gt_boxes  = (const float*)d_in[1];
  const float* features  = (const float*)d_in[2];
  const float* W1   = (const float*)d_in[3];
  const float* b1   = (const float*)d_in[4];
  const float* W2   = (const float*)d_in[5];
  const float* b2   = (const float*)d_in[6];
  const float* Wcls = (const float*)d_in[7];
  const float* bcls = (const float*)d_in[8];
  const float* Wbox = (const float*)d_in[9];
  const float* bbox = (const float*)d_in[10];
  const int* gt_labels = (const int*)d_in[11];
  float* out = (float*)d_out;

  char* ws = (char*)d_ws;
  unsigned short* feat_bf = (unsigned short*)(ws + O_FEAT);
  unsigned short* W1t  = (unsigned short*)(ws + O_W1T);
  unsigned short* W2t  = (unsigned short*)(ws + O_W2T);
  unsigned short* Wh   = (unsigned short*)(ws + O_WH);
  float* bh            = (float*)(ws + O_BH);
  unsigned short* x1   = (unsigned short*)(ws + O_X1);
  unsigned short* x2   = (unsigned short*)(ws + O_X2);
  float* head_out      = (float*)(ws + O_HO);
  int* labels          = (int*)(ws + O_LAB);
  float* tgts          = (float*)(ws + O_TGT);
  float* nll_v         = (float*)(ws + O_NLL);
  float* vc_v          = (float*)(ws + O_VC);
  float* sl1_v         = (float*)(ws + O_SL1);
  float* part          = (float*)(ws + O_PART);

  const bool big_ws = (ws_size >= O_PART + SZ_P4);  // split-4 partials fit?

  // 1. feature fp32 -> bf16
  convert_bf16<<<2048, 256, 0, stream>>>(features, feat_bf, (long)RT * FEATD / 4);
  // 2. weight transposes (to B^T layout) + fused head
  transpose_conv<<<dim3(REPD / 32, FEATD / 32), dim3(32, 8), 0, stream>>>(W1, W1t, FEATD, REPD, 0, FEATD);
  transpose_conv<<<dim3(REPD / 32, REPD / 32), dim3(32, 8), 0, stream>>>(W2, W2t, REPD, REPD, 0, REPD);
  transpose_conv<<<dim3((CC + 31) / 32, REPD / 32), dim3(32, 8), 0, stream>>>(Wcls, Wh, REPD, CC, 0, REPD);
  transpose_conv<<<dim3((4 * CC + 31) / 32, REPD / 32), dim3(32, 8), 0, stream>>>(Wbox, Wh, REPD, 4 * CC, CC, REPD);
  head_init<<<228, 256, 0, stream>>>(Wh, bh, bcls, bbox);
  // 3. matcher + encode
  matcher_kernel<<<(RT + 255) / 256, 256, 0, stream>>>(proposals, gt_boxes, gt_labels, labels, tgts);

  // 4. MLP + heads (split-K for occupancy: grid must exceed 256 CUs)
  if (big_ws) {
    gemm_lds<<<dim3(REPD / 128, RT / 128, 4), 256, 0, stream>>>(feat_bf, W1t, part, RT, REPD, FEATD, FEATD / 4);
    reduce_split<4, true, true><<<1056, 256, 0, stream>>>(part, b1, x1, RT, REPD);
  } else {
    gemm_lds<<<dim3(REPD / 128, RT / 128, 2), 256, 0, stream>>>(feat_bf, W1t, part, RT, REPD, FEATD, FEATD / 2);
    reduce_split<2, true, true><<<1056, 256, 0, stream>>>(part, b1, x1, RT, REPD);
  }
  gemm_lds<<<dim3(REPD / 128, RT / 128, 2), 256, 0, stream>>>(x1, W2t, part, RT, REPD, REPD, REPD / 2);
  reduce_split<2, true, true><<<1056, 256, 0, stream>>>(part, b2, x2, RT, REPD);
  gemm_lds<<<dim3(NH / 128, RT / 128, 2), 256, 0, stream>>>(x2, Wh, part, RT, NH, REPD, REPD / 2);
  reduce_split<2, false, false><<<528, 256, 0, stream>>>(part, bh, head_out, RT, NH);

  // 5. losses
  loss_row<<<RT, 64, 0, stream>>>(head_out, labels, tgts, nll_v, vc_v, sl1_v);
  reduce_final<<<1, 256, 0, stream>>>(nll_v, vc_v, sl1_v, out);
}

// Round 3
// 632.309 us; speedup vs baseline: 1.1104x; 1.0086x over previous
//
#include <hip/hip_runtime.h>
#include <cstdint>
#include <cstddef>

// ---- problem constants ----
#define BQ   8
#define NP   512
#define GQ   16
#define PP   528      // NP + GQ
#define RT   4224     // BQ * PP
#define CC   91
#define FEATD 12544
#define REPD 1024
#define NH   512      // padded head output cols (455 used: 91 cls + 364 box)
#define NHU  455
#define BETA (1.0f/9.0f)

typedef __bf16 bf16x8 __attribute__((ext_vector_type(8)));
typedef float  f32x4  __attribute__((ext_vector_type(4)));

__device__ __forceinline__ unsigned short f2bf(float f) {
  unsigned int x = __float_as_uint(f);
  unsigned int r = (x + 0x7fffu + ((x >> 16) & 1u)) >> 16;
  return (unsigned short)r;
}

// async global->LDS DMA, 16 B per lane; HW writes lane L to base + L*16.
__device__ __forceinline__ void ld_lds16(const void* g, void* l) {
  __builtin_amdgcn_global_load_lds(
      (const __attribute__((address_space(1))) void*)g,
      (__attribute__((address_space(3))) void*)l, 16, 0, 0);
}

// ---- workspace layout (bytes); total ~115.5 MB (ws >= 161 MB proven round 1) ----
constexpr size_t O_W1T = 0;
constexpr size_t SZ_W1T = (size_t)FEATD * REPD * 2;         // W1^T bf16 [1024][12544]
constexpr size_t O_W2T = O_W1T + SZ_W1T;
constexpr size_t SZ_W2T = (size_t)REPD * REPD * 2;          // W2^T bf16 [1024][1024]
constexpr size_t O_WH  = O_W2T + SZ_W2T;
constexpr size_t SZ_WH = (size_t)NH * REPD * 2;             // [Wcls|Wbox]^T bf16 [512][1024]
constexpr size_t O_BH  = O_WH + SZ_WH;
constexpr size_t SZ_BH = (size_t)NH * 4;
constexpr size_t O_X1  = O_BH + SZ_BH;
constexpr size_t SZ_X1 = (size_t)RT * REPD * 2;             // x1 bf16
constexpr size_t O_X2  = O_X1 + SZ_X1;
constexpr size_t O_LAB = O_X2 + SZ_X1;
constexpr size_t O_TGT = O_LAB + (size_t)RT * 4;
constexpr size_t O_NLL = O_TGT + (size_t)RT * 16;
constexpr size_t O_VC  = O_NLL + (size_t)RT * 4;
constexpr size_t O_SL1 = O_VC + (size_t)RT * 4;
constexpr size_t O_PART = ((O_SL1 + (size_t)RT * 4) + 255) & ~(size_t)255;
constexpr size_t SZ_P4 = (size_t)4 * RT * REPD * 4;         // 69.2 MB split-K partials

// ---- prep mega-kernel: 4 transposes + head pad/bias + matcher, by block range ----
__device__ __forceinline__ void t32(const float* __restrict__ in, unsigned short* __restrict__ out,
                                    int K, int N, int row_off, int out_ld,
                                    int bx, int by, int t, float (*tile)[33]) {
  int tx = t & 31, ty = t >> 5;
  int n0 = bx * 32, k0 = by * 32;
#pragma unroll
  for (int i = 0; i < 4; ++i) {
    int k = k0 + ty + i * 8, n = n0 + tx;
    if (k < K && n < N) tile[ty + i * 8][tx] = in[(size_t)k * N + n];
  }
  __syncthreads();
#pragma unroll
  for (int i = 0; i < 4; ++i) {
    int n = n0 + ty + i * 8, k = k0 + tx;
    if (n < N && k < K) out[(size_t)(n + row_off) * out_ld + k] = f2bf(tile[tx][ty + i * 8]);
  }
}

#define NB_W1 ((REPD/32)*(FEATD/32))   // 12544
#define NB_W2 ((REPD/32)*(REPD/32))    // 1024
#define NB_WC (3*(REPD/32))            // 96
#define NB_WB (12*(REPD/32))           // 384
#define NB_HI 230
#define NB_MT 17
#define NB_PREP (NB_W1+NB_W2+NB_WC+NB_WB+NB_HI+NB_MT)

__global__ void prep(const float* __restrict__ W1, const float* __restrict__ W2,
                     const float* __restrict__ Wcls, const float* __restrict__ Wbox,
                     const float* __restrict__ bcls, const float* __restrict__ bbox,
                     const float* __restrict__ proposals, const float* __restrict__ gt_boxes,
                     const int* __restrict__ gt_labels,
                     unsigned short* __restrict__ W1t, unsigned short* __restrict__ W2t,
                     unsigned short* __restrict__ Wh, float* __restrict__ bh,
                     int* __restrict__ labels, float* __restrict__ tgts) {
  __shared__ float tile[32][33];
  int b = blockIdx.x, t = threadIdx.x;
  if (b < NB_W1) { t32(W1, W1t, FEATD, REPD, 0, FEATD, b % (REPD/32), b / (REPD/32), t, tile); return; }
  b -= NB_W1;
  if (b < NB_W2) { t32(W2, W2t, REPD, REPD, 0, REPD, b % 32, b / 32, t, tile); return; }
  b -= NB_W2;
  if (b < NB_WC) { t32(Wcls, Wh, REPD, CC, 0, REPD, b % 3, b / 3, t, tile); return; }
  b -= NB_WC;
  if (b < NB_WB) { t32(Wbox, Wh, REPD, 4 * CC, CC, REPD, b % 12, b / 12, t, tile); return; }
  b -= NB_WB;
  if (b < NB_HI) {
    int idx = b * 256 + t;
    const int npad = (NH - NHU) * REPD;   // 58368
    if (idx < npad) Wh[(size_t)NHU * REPD + idx] = 0;
    else {
      int i2 = idx - npad;
      if (i2 < NH) bh[i2] = (i2 < CC) ? bcls[i2] : (i2 < NHU ? bbox[i2 - CC] : 0.0f);
    }
    return;
  }
  b -= NB_HI;
  // ---- matcher + encode ----
  int r = b * 256 + t;
  if (r >= RT) return;
  int bi_ = r / PP, p = r % PP;
  float x0, y0, x1, y1;
  if (p < NP) {
    const float* qq = proposals + ((size_t)bi_ * NP + p) * 4;
    x0 = qq[0]; y0 = qq[1]; x1 = qq[2]; y1 = qq[3];
  } else {
    const float* qq = gt_boxes + ((size_t)bi_ * GQ + (p - NP)) * 4;
    x0 = qq[0]; y0 = qq[1]; x1 = qq[2]; y1 = qq[3];
  }
  float ap = (x1 - x0) * (y1 - y0);
  float best = -1.0f; int bg = 0;
#pragma unroll
  for (int g = 0; g < GQ; ++g) {
    const float* gb = gt_boxes + ((size_t)bi_ * GQ + g) * 4;
    float gx0 = gb[0], gy0 = gb[1], gx1 = gb[2], gy1 = gb[3];
    float ag = (gx1 - gx0) * (gy1 - gy0);
    float iw = fmaxf(fminf(gx1, x1) - fmaxf(gx0, x0), 0.0f);
    float ih = fmaxf(fminf(gy1, y1) - fmaxf(gy0, y0), 0.0f);
    float inter = iw * ih;
    float iou = inter / (ag + ap - inter);
    if (iou > best) { best = iou; bg = g; }   // strict > keeps first max (jnp.argmax)
  }
  int lab = gt_labels[bi_ * GQ + bg];
  if (best < 0.5f) lab = 0;    // FG==BG==0.5 -> ignore band empty
  labels[r] = lab;
  const float* gb = gt_boxes + ((size_t)bi_ * GQ + bg) * 4;
  float ew = x1 - x0, eh = y1 - y0;
  float ex = x0 + 0.5f * ew, ey = y0 + 0.5f * eh;
  float gw = gb[2] - gb[0], gh = gb[3] - gb[1];
  float gx = gb[0] + 0.5f * gw, gy = gb[1] + 0.5f * gh;
  tgts[r * 4 + 0] = 10.0f * (gx - ex) / ew;
  tgts[r * 4 + 1] = 10.0f * (gy - ey) / eh;
  tgts[r * 4 + 2] = 5.0f * logf(gw / ew);
  tgts[r * 4 + 3] = 5.0f * logf(gh / eh);
}

// ---- bf16 MFMA GEMM, 64Mx128N tile, BK=32, split-K, XCD-clustered 1D grid ----
// AFP32: A is fp32, staged via regular loads + in-register bf16 pack + swizzled
// ds_write_b128 (2-way conflicts = free). B always via global_load_lds DMA with
// fetch-side XOR swizzle. Fragment reads identical to verified round-2 layout.
// P[kz][M][Nc] = partial products (fp32).
template <bool AFP32>
__global__ __launch_bounds__(256, 6)
void gemm_k(const void* __restrict__ Aptr, const unsigned short* __restrict__ Bt,
            float* __restrict__ P, int M, int Nc, int K, int Kspl, int nkz,
            int slots_pad, int nreal) {
  __shared__ unsigned short As[64 * 32];
  __shared__ unsigned short Bs[128 * 32];

  const int g = blockIdx.x;
  const int slot = g % slots_pad;          // slots_pad % 8 == 0 -> same slot%8 -> same XCD
  const int nb = g / slots_pad;
  if (slot >= nreal) return;               // uniform dummy-block exit (no barriers yet)
  const int mi = slot / nkz;
  const int kz = slot - mi * nkz;
  const int m0 = mi * 64, n0 = nb * 128;

  const int tid = threadIdx.x;
  const int w = tid >> 6, L = tid & 63;
  const int q = L >> 4, l16 = L & 15;
  const int wm = (w >> 1) * 32, wn = (w & 1) * 64;
  const size_t kbase = (size_t)kz * Kspl;

  // DMA seg geometry: seg = 16 rows x 32 bf16 = 1 KB; lane L -> row seg*16+(L>>2),
  // fetch chunk (L&3)^((row>>1)&3) = (L&3)^((L>>3)&3)  (seg-independent).
  const int lrow = L >> 2;
  const int lchk = ((L & 3) ^ ((L >> 3) & 3)) * 8;

  constexpr int NSEG = AFP32 ? 2 : 3;
  const unsigned short* gsrc[NSEG];
  unsigned short* ldst[NSEG];
  const float* Af = (const float*)Aptr;
  const unsigned short* Ab = (const unsigned short*)Aptr;
  if (AFP32) {
    // B only: 8 segs over 4 waves
#pragma unroll
    for (int v = 0; v < NSEG; ++v) {
      int sg = 2 * w + v;
      gsrc[v] = Bt + (size_t)(n0 + sg * 16 + lrow) * K + kbase + lchk;
      ldst[v] = &Bs[sg * 512];
    }
  } else {
    // A(4 segs) + B(8 segs) over 4 waves
#pragma unroll
    for (int v = 0; v < NSEG; ++v) {
      int sg = 3 * w + v;
      if (sg < 4) {
        gsrc[v] = Ab + (size_t)(m0 + sg * 16 + lrow) * K + kbase + lchk;
        ldst[v] = &As[sg * 512];
      } else {
        int s2 = sg - 4;
        gsrc[v] = Bt + (size_t)(n0 + s2 * 16 + lrow) * K + kbase + lchk;
        ldst[v] = &Bs[s2 * 512];
      }
    }
  }

  // fp32-A staging: thread -> row tid>>2 (0..63), chunk tid&3; swizzled LDS dest
  const int sr = tid >> 2;
  const int scnk = tid & 3;
  const float* Ag = nullptr;
  unsigned short* Asw = nullptr;
  if (AFP32) {
    Ag  = Af + (size_t)(m0 + sr) * K + kbase + scnk * 8;
    Asw = &As[sr * 32 + (scnk ^ ((sr >> 1) & 3)) * 8];
  }

  // fragment LDS addresses (swizzle folded), constant across K-loop
  const unsigned short* afp[2];
  const unsigned short* bfp[4];
#pragma unroll
  for (int i = 0; i < 2; ++i) {
    int ra = wm + i * 16 + l16;
    afp[i] = &As[ra * 32 + (q ^ ((ra >> 1) & 3)) * 8];
  }
#pragma unroll
  for (int j = 0; j < 4; ++j) {
    int rb = wn + j * 16 + l16;
    bfp[j] = &Bs[rb * 32 + (q ^ ((rb >> 1) & 3)) * 8];
  }

  f32x4 acc[2][4] = {};
  const int nk = Kspl >> 5;
  float4 pf0, pf1;
  if constexpr (AFP32) { pf0 = *(const float4*)Ag; pf1 = *(const float4*)(Ag + 4); }

  for (int kb = 0; kb < nk; ++kb) {
    const int ko = kb * 32;
#pragma unroll
    for (int v = 0; v < NSEG; ++v) ld_lds16(gsrc[v] + ko, ldst[v]);
    if constexpr (AFP32) {
      uint4 pk;
      pk.x = (unsigned)f2bf(pf0.x) | ((unsigned)f2bf(pf0.y) << 16);
      pk.y = (unsigned)f2bf(pf0.z) | ((unsigned)f2bf(pf0.w) << 16);
      pk.z = (unsigned)f2bf(pf1.x) | ((unsigned)f2bf(pf1.y) << 16);
      pk.w = (unsigned)f2bf(pf1.z) | ((unsigned)f2bf(pf1.w) << 16);
      *(uint4*)Asw = pk;
    }
    __syncthreads();   // drains DMA (vm) + ds_write (lgkm); tile staged
    if constexpr (AFP32) {
      if (kb + 1 < nk) {   // register prefetch overlaps MFMAs
        pf0 = *(const float4*)(Ag + ko + 32);
        pf1 = *(const float4*)(Ag + ko + 36);
      }
    }
    bf16x8 af[2], bfr[4];
#pragma unroll
    for (int i = 0; i < 2; ++i) af[i] = *(const bf16x8*)afp[i];
#pragma unroll
    for (int j = 0; j < 4; ++j) bfr[j] = *(const bf16x8*)bfp[j];
#pragma unroll
    for (int i = 0; i < 2; ++i)
#pragma unroll
      for (int j = 0; j < 4; ++j)
        acc[i][j] = __builtin_amdgcn_mfma_f32_16x16x32_bf16(af[i], bfr[j], acc[i][j], 0, 0, 0);
    __syncthreads();   // protect LDS from next iteration's staging
  }

  // epilogue: D[row=q*4+r][col=l16] (verified layout) -> fp32 partials
  float* Pz = P + (size_t)kz * M * Nc;
#pragma unroll
  for (int i = 0; i < 2; ++i) {
    int rowb = m0 + wm + i * 16 + q * 4;
#pragma unroll
    for (int j = 0; j < 4; ++j) {
      int col = n0 + wn + j * 16 + l16;
#pragma unroll
      for (int r = 0; r < 4; ++r)
        Pz[(size_t)(rowb + r) * Nc + col] = acc[i][j][r];
    }
  }
}

// ---- split-K reduce + bias (+ReLU) (+bf16 cast) ----
template <int S, bool RELU, bool BF16OUT>
__global__ void reduce_split(const float* __restrict__ P, const float* __restrict__ bias,
                             void* __restrict__ outp, int M, int Nc) {
  const long MN4 = (long)M * Nc / 4;
  const int nc4 = Nc / 4;
  long i = (long)blockIdx.x * blockDim.x + threadIdx.x;
  long stride = (long)gridDim.x * blockDim.x;
  const float4* P4 = (const float4*)P;
  const float4* B4 = (const float4*)bias;
  for (; i < MN4; i += stride) {
    float4 v = P4[i];
#pragma unroll
    for (int s = 1; s < S; ++s) {
      float4 u = P4[s * MN4 + i];
      v.x += u.x; v.y += u.y; v.z += u.z; v.w += u.w;
    }
    float4 b = B4[i % nc4];
    v.x += b.x; v.y += b.y; v.z += b.z; v.w += b.w;
    if (RELU) {
      v.x = fmaxf(v.x, 0.f); v.y = fmaxf(v.y, 0.f);
      v.z = fmaxf(v.z, 0.f); v.w = fmaxf(v.w, 0.f);
    }
    if (BF16OUT) {
      ushort4 u; u.x = f2bf(v.x); u.y = f2bf(v.y); u.z = f2bf(v.z); u.w = f2bf(v.w);
      ((ushort4*)outp)[i] = u;
    } else {
      ((float4*)outp)[i] = v;
    }
  }
}

// ---- per-row loss, reading GEMM3's 2 split-K partial slices + bias directly ----
__global__ void loss_row(const float* __restrict__ P, const float* __restrict__ bh,
                         const int* __restrict__ labels, const float* __restrict__ tgts,
                         float* __restrict__ nll_v, float* __restrict__ vc_v,
                         float* __restrict__ sl1_v) {
  int r = blockIdx.x;
  int l = threadIdx.x;
  const float* p0 = P + (size_t)r * NH;
  const float* p1 = p0 + (size_t)RT * NH;
  float v1 = p0[l] + p1[l] + bh[l];
  float v2 = (l < CC - 64) ? (p0[64 + l] + p1[64 + l] + bh[64 + l]) : -3.4e38f;
  float m = fmaxf(v1, v2);
#pragma unroll
  for (int o = 32; o; o >>= 1) m = fmaxf(m, __shfl_xor(m, o));
  float e = __expf(v1 - m) + ((l < CC - 64) ? __expf(v2 - m) : 0.0f);
#pragma unroll
  for (int o = 32; o; o >>= 1) e += __shfl_xor(e, o);
  if (l == 0) {
    float lse = m + __logf(e);
    int lab = labels[r];
    int sl = lab < 0 ? 0 : (lab > CC - 1 ? CC - 1 : lab);
    float valid = (lab >= 0) ? 1.0f : 0.0f;
    nll_v[r] = (lse - (p0[sl] + p1[sl] + bh[sl])) * valid;
    vc_v[r] = valid;
    float s = 0.0f;
#pragma unroll
    for (int d = 0; d < 4; ++d) {
      int c = CC + sl * 4 + d;
      float pd = p0[c] + p1[c] + bh[c];
      float ad = fabsf(pd - tgts[r * 4 + d]);
      s += (ad < BETA) ? 0.5f * ad * ad / BETA : ad - 0.5f * BETA;
    }
    sl1_v[r] = (lab > 0) ? s : 0.0f;
  }
}

// ---- deterministic final reduce ----
__global__ void reduce_final(const float* __restrict__ nll_v, const float* __restrict__ vc_v,
                             const float* __restrict__ sl1_v, float* __restrict__ out) {
  __shared__ float s1[256], s2[256], s3[256];
  int t = threadIdx.x;
  float a = 0, b = 0, c = 0;
  for (int i = t; i < RT; i += 256) { a += nll_v[i]; b += vc_v[i]; c += sl1_v[i]; }
  s1[t] = a; s2[t] = b; s3[t] = c;
  __syncthreads();
  for (int o = 128; o; o >>= 1) {
    if (t < o) { s1[t] += s1[t + o]; s2[t] += s2[t + o]; s3[t] += s3[t + o]; }
    __syncthreads();
  }
  if (t == 0) {
    out[0] = s1[0] / fmaxf(s2[0], 1.0f);
    out[1] = s3[0] / (float)RT;
  }
}

extern "C" void kernel_launch(void* const* d_in, const int* in_sizes, int n_in,
                              void* d_out, int out_size, void* d_ws, size_t ws_size,
                              hipStream_t stream) {
  const float* proposals = (const float*)d_in[0];
  const float* gt_boxes  = (const float*)d_in[1];
  const float* features  = (const float*)d_in[2];
  const float* W1   = (const float*)d_in[3];
  const float* b1   = (const float*)d_in[4];
  const float* W2   = (const float*)d_in[5];
  const float* b2   = (const float*)d_in[6];
  const float* Wcls = (const float*)d_in[7];
  const float* bcls = (const float*)d_in[8];
  const float* Wbox = (const float*)d_in[9];
  const float* bbox = (const float*)d_in[10];
  const int* gt_labels = (const int*)d_in[11];
  float* out = (float*)d_out;

  char* ws = (char*)d_ws;
  unsigned short* W1t = (unsigned short*)(ws + O_W1T);
  unsigned short* W2t = (unsigned short*)(ws + O_W2T);
  unsigned short* Wh  = (unsigned short*)(ws + O_WH);
  float* bh           = (float*)(ws + O_BH);
  unsigned short* x1  = (unsigned short*)(ws + O_X1);
  unsigned short* x2  = (unsigned short*)(ws + O_X2);
  int* labels         = (int*)(ws + O_LAB);
  float* tgts         = (float*)(ws + O_TGT);
  float* nll_v        = (float*)(ws + O_NLL);
  float* vc_v         = (float*)(ws + O_VC);
  float* sl1_v        = (float*)(ws + O_SL1);
  float* part         = (float*)(ws + O_PART);

  // 1. prep: all weight transposes + head init + matcher in one launch
  prep<<<NB_PREP, 256, 0, stream>>>(W1, W2, Wcls, Wbox, bcls, bbox,
                                    proposals, gt_boxes, gt_labels,
                                    W1t, W2t, Wh, bh, labels, tgts);

  // 2. GEMM1: [4224,12544]fp32 x W1t -> split-4 partials; slots=66*4=264 (264%8==0)
  gemm_k<true><<<264 * 8, 256, 0, stream>>>(features, W1t, part, RT, REPD,
                                            FEATD, FEATD / 4, 4, 264, 264);
  reduce_split<4, true, true><<<1056, 256, 0, stream>>>(part, b1, x1, RT, REPD);

  // 3. GEMM2: x1 x W2t -> split-2; slots=66*2=132, padded to 136 (136%8==0)
  gemm_k<false><<<136 * 8, 256, 0, stream>>>(x1, W2t, part, RT, REPD,
                                             REPD, REPD / 2, 2, 136, 132);
  reduce_split<2, true, true><<<1056, 256, 0, stream>>>(part, b2, x2, RT, REPD);

  // 4. GEMM3: x2 x Wh -> split-2 partials, consumed directly by loss_row
  gemm_k<false><<<136 * 4, 256, 0, stream>>>(x2, Wh, part, RT, NH,
                                             REPD, REPD / 2, 2, 136, 132);

  // 5. losses
  loss_row<<<RT, 64, 0, stream>>>(part, bh, labels, tgts, nll_v, vc_v, sl1_v);
  reduce_final<<<1, 256, 0, stream>>>(nll_v, vc_v, sl1_v, out);
}

// Round 4
// 627.595 us; speedup vs baseline: 1.1188x; 1.0075x over previous
//
#include <hip/hip_runtime.h>
#include <cstdint>
#include <cstddef>

// ---- problem constants ----
#define BQ   8
#define NP   512
#define GQ   16
#define PP   528      // NP + GQ
#define RT   4224     // BQ * PP
#define CC   91
#define FEATD 12544
#define REPD 1024
#define NH   512      // padded head output cols (455 used: 91 cls + 364 box)
#define NHU  455
#define BETA (1.0f/9.0f)

typedef __bf16 bf16x8 __attribute__((ext_vector_type(8)));
typedef float  f32x4  __attribute__((ext_vector_type(4)));

__device__ __forceinline__ unsigned short f2bf(float f) {
  unsigned int x = __float_as_uint(f);
  unsigned int r = (x + 0x7fffu + ((x >> 16) & 1u)) >> 16;
  return (unsigned short)r;
}

// async global->LDS DMA, 16 B per lane; HW writes lane L to base + L*16.
__device__ __forceinline__ void ld_lds16(const void* g, void* l) {
  __builtin_amdgcn_global_load_lds(
      (const __attribute__((address_space(1))) void*)g,
      (__attribute__((address_space(3))) void*)l, 16, 0, 0);
}

// ---- workspace layout (bytes); total ~221.5 MB.
// ws >= 230.6 MB proven: round-2 ran the big_ws split-4 branch (WRITE_SIZE
// 67.6 MB == 4224*1024*4slices*4B), whose guard required O_PART(161.4M)+69.2M.
constexpr size_t O_W1T = 0;
constexpr size_t SZ_W1T = (size_t)FEATD * REPD * 2;         // W1^T bf16 [1024][12544]
constexpr size_t O_W2T = O_W1T + SZ_W1T;
constexpr size_t SZ_W2T = (size_t)REPD * REPD * 2;          // W2^T bf16 [1024][1024]
constexpr size_t O_WH  = O_W2T + SZ_W2T;
constexpr size_t SZ_WH = (size_t)NH * REPD * 2;             // [Wcls|Wbox]^T bf16 [512][1024]
constexpr size_t O_BH  = O_WH + SZ_WH;
constexpr size_t SZ_BH = (size_t)NH * 4;
constexpr size_t O_X1  = O_BH + SZ_BH;
constexpr size_t SZ_X1 = (size_t)RT * REPD * 2;             // x1 bf16
constexpr size_t O_X2  = O_X1 + SZ_X1;
constexpr size_t O_LAB = O_X2 + SZ_X1;
constexpr size_t O_TGT = O_LAB + (size_t)RT * 4;
constexpr size_t O_NLL = O_TGT + (size_t)RT * 16;
constexpr size_t O_VC  = O_NLL + (size_t)RT * 4;
constexpr size_t O_SL1 = O_VC + (size_t)RT * 4;
constexpr size_t O_PART = ((O_SL1 + (size_t)RT * 4) + 255) & ~(size_t)255;
constexpr size_t SZ_P4 = (size_t)4 * RT * REPD * 4;         // 69.2 MB split-K partials
constexpr size_t O_FEAT = O_PART + SZ_P4;                   // bf16 features, 106 MB

// ---- prep mega-kernel: feature convert + 4 transposes + head init + matcher ----
__device__ __forceinline__ void t32(const float* __restrict__ in, unsigned short* __restrict__ out,
                                    int K, int N, int row_off, int out_ld,
                                    int bx, int by, int t, float (*tile)[33]) {
  int tx = t & 31, ty = t >> 5;
  int n0 = bx * 32, k0 = by * 32;
#pragma unroll
  for (int i = 0; i < 4; ++i) {
    int k = k0 + ty + i * 8, n = n0 + tx;
    if (k < K && n < N) tile[ty + i * 8][tx] = in[(size_t)k * N + n];
  }
  __syncthreads();
#pragma unroll
  for (int i = 0; i < 4; ++i) {
    int n = n0 + ty + i * 8, k = k0 + tx;
    if (n < N && k < K) out[(size_t)(n + row_off) * out_ld + k] = f2bf(tile[tx][ty + i * 8]);
  }
}

#define NB_CV ((RT * FEATD / 4) / 256)   // 51744 feature-convert blocks (4 elem/thr)
#define NB_W1 ((REPD/32)*(FEATD/32))     // 12544
#define NB_W2 ((REPD/32)*(REPD/32))      // 1024
#define NB_WC (3*(REPD/32))              // 96
#define NB_WB (12*(REPD/32))             // 384
#define NB_HI 230
#define NB_MT 17
#define NB_PREP (NB_CV+NB_W1+NB_W2+NB_WC+NB_WB+NB_HI+NB_MT)

__global__ void prep(const float* __restrict__ feat, unsigned short* __restrict__ feat_bf,
                     const float* __restrict__ W1, const float* __restrict__ W2,
                     const float* __restrict__ Wcls, const float* __restrict__ Wbox,
                     const float* __restrict__ bcls, const float* __restrict__ bbox,
                     const float* __restrict__ proposals, const float* __restrict__ gt_boxes,
                     const int* __restrict__ gt_labels,
                     unsigned short* __restrict__ W1t, unsigned short* __restrict__ W2t,
                     unsigned short* __restrict__ Wh, float* __restrict__ bh,
                     int* __restrict__ labels, float* __restrict__ tgts) {
  __shared__ float tile[32][33];
  int b = blockIdx.x, t = threadIdx.x;
  if (b < NB_CV) {
    long i = (long)b * 256 + t;
    float4 f = ((const float4*)feat)[i];
    ushort4 u;
    u.x = f2bf(f.x); u.y = f2bf(f.y); u.z = f2bf(f.z); u.w = f2bf(f.w);
    ((ushort4*)feat_bf)[i] = u;
    return;
  }
  b -= NB_CV;
  if (b < NB_W1) { t32(W1, W1t, FEATD, REPD, 0, FEATD, b % (REPD/32), b / (REPD/32), t, tile); return; }
  b -= NB_W1;
  if (b < NB_W2) { t32(W2, W2t, REPD, REPD, 0, REPD, b % 32, b / 32, t, tile); return; }
  b -= NB_W2;
  if (b < NB_WC) { t32(Wcls, Wh, REPD, CC, 0, REPD, b % 3, b / 3, t, tile); return; }
  b -= NB_WC;
  if (b < NB_WB) { t32(Wbox, Wh, REPD, 4 * CC, CC, REPD, b % 12, b / 12, t, tile); return; }
  b -= NB_WB;
  if (b < NB_HI) {
    int idx = b * 256 + t;
    const int npad = (NH - NHU) * REPD;   // 58368
    if (idx < npad) Wh[(size_t)NHU * REPD + idx] = 0;
    else {
      int i2 = idx - npad;
      if (i2 < NH) bh[i2] = (i2 < CC) ? bcls[i2] : (i2 < NHU ? bbox[i2 - CC] : 0.0f);
    }
    return;
  }
  b -= NB_HI;
  // ---- matcher + encode ----
  int r = b * 256 + t;
  if (r >= RT) return;
  int bi_ = r / PP, p = r % PP;
  float x0, y0, x1, y1;
  if (p < NP) {
    const float* qq = proposals + ((size_t)bi_ * NP + p) * 4;
    x0 = qq[0]; y0 = qq[1]; x1 = qq[2]; y1 = qq[3];
  } else {
    const float* qq = gt_boxes + ((size_t)bi_ * GQ + (p - NP)) * 4;
    x0 = qq[0]; y0 = qq[1]; x1 = qq[2]; y1 = qq[3];
  }
  float ap = (x1 - x0) * (y1 - y0);
  float best = -1.0f; int bg = 0;
#pragma unroll
  for (int g = 0; g < GQ; ++g) {
    const float* gb = gt_boxes + ((size_t)bi_ * GQ + g) * 4;
    float gx0 = gb[0], gy0 = gb[1], gx1 = gb[2], gy1 = gb[3];
    float ag = (gx1 - gx0) * (gy1 - gy0);
    float iw = fmaxf(fminf(gx1, x1) - fmaxf(gx0, x0), 0.0f);
    float ih = fmaxf(fminf(gy1, y1) - fmaxf(gy0, y0), 0.0f);
    float inter = iw * ih;
    float iou = inter / (ag + ap - inter);
    if (iou > best) { best = iou; bg = g; }   // strict > keeps first max (jnp.argmax)
  }
  int lab = gt_labels[bi_ * GQ + bg];
  if (best < 0.5f) lab = 0;    // FG==BG==0.5 -> ignore band empty
  labels[r] = lab;
  const float* gb = gt_boxes + ((size_t)bi_ * GQ + bg) * 4;
  float ew = x1 - x0, eh = y1 - y0;
  float ex = x0 + 0.5f * ew, ey = y0 + 0.5f * eh;
  float gw = gb[2] - gb[0], gh = gb[3] - gb[1];
  float gx = gb[0] + 0.5f * gw, gy = gb[1] + 0.5f * gh;
  tgts[r * 4 + 0] = 10.0f * (gx - ex) / ew;
  tgts[r * 4 + 1] = 10.0f * (gy - ey) / eh;
  tgts[r * 4 + 2] = 5.0f * logf(gw / ew);
  tgts[r * 4 + 3] = 5.0f * logf(gh / eh);
}

// ---- bf16 MFMA GEMM: 128x128 tile, BK=32, double-buffered DMA staging ----
// Round-2 structure (proven 0 conflicts) + LDS dbuf: DMA for tile k+1 is issued
// BEFORE computing tile k, so the barrier's vmcnt(0) drain lands after compute
// and DMA latency overlaps MFMA. 1 barrier/iter. LDS 32 KB -> still 4 blocks/CU.
// P[kz][M][Nc] = fp32 partials. Requires nk >= 2.
__global__ __launch_bounds__(256, 4)
void gemm_db(const unsigned short* __restrict__ A, const unsigned short* __restrict__ Bt,
             float* __restrict__ P, int M, int Nc, int K, int Kspl) {
  constexpr int BUF = 128 * 32;           // elements per buffer
  __shared__ unsigned short As[2 * BUF];
  __shared__ unsigned short Bs[2 * BUF];

  const int tid = threadIdx.x;
  const int m0 = blockIdx.y * 128;
  const int n0 = blockIdx.x * 128;
  const int kz = blockIdx.z;
  const int w = tid >> 6, L = tid & 63;
  const int q = L >> 4, l16 = L & 15;
  const int wr = (w >> 1) * 64, wc = (w & 1) * 64;
  const size_t kbase = (size_t)kz * Kspl;

  // DMA seg geometry: seg = 16 rows x 32 bf16 = 1 KB; lane L -> row (L>>2),
  // fetches swizzled chunk (L&3)^((row>>1)&3) = (L&3)^((L>>3)&3).
  const int lrow = L >> 2;
  const int lchk = ((L & 3) ^ ((L >> 3) & 3)) * 8;
  const int s0 = w * 2;
  const int r0 = s0 * 16 + lrow, r1 = r0 + 16;

  const unsigned short* gsrc[4];
  gsrc[0] = A  + (size_t)(m0 + r0) * K + kbase + lchk;
  gsrc[1] = A  + (size_t)(m0 + r1) * K + kbase + ((lchk ^ 0) /*same formula*/);
  gsrc[1] = A  + (size_t)(m0 + r1) * K + kbase + lchk;
  gsrc[2] = Bt + (size_t)(n0 + r0) * K + kbase + lchk;
  gsrc[3] = Bt + (size_t)(n0 + r1) * K + kbase + lchk;
  unsigned short* ldst[4];
  ldst[0] = &As[(s0)     * 512];
  ldst[1] = &As[(s0 + 1) * 512];
  ldst[2] = &Bs[(s0)     * 512];
  ldst[3] = &Bs[(s0 + 1) * 512];

  // fragment LDS element-offsets (swizzle folded), constant across K-loop
  int afo[4], bfo[4];
#pragma unroll
  for (int i = 0; i < 4; ++i) {
    int ra = wr + i * 16 + l16;
    afo[i] = ra * 32 + (q ^ ((ra >> 1) & 3)) * 8;
    int rb = wc + i * 16 + l16;
    bfo[i] = rb * 32 + (q ^ ((rb >> 1) & 3)) * 8;
  }

  f32x4 acc[4][4] = {};
  const int nk = Kspl >> 5;

  // prologue: stage tile 0 into buffer 0
#pragma unroll
  for (int v = 0; v < 4; ++v) ld_lds16(gsrc[v], ldst[v]);
  __syncthreads();

  int cur = 0;
  for (int kb = 0; kb < nk; ++kb) {
    // prefetch tile kb+1 into the other buffer BEFORE computing tile kb
    if (kb + 1 < nk) {
      const int ko = (kb + 1) * 32;
      const int nof = (cur ^ 1) * BUF;
#pragma unroll
      for (int v = 0; v < 4; ++v) ld_lds16(gsrc[v] + ko, ldst[v] + nof);
    }
    const int cof = cur * BUF;
    bf16x8 af[4], bfr[4];
#pragma unroll
    for (int i = 0; i < 4; ++i) af[i]  = *(const bf16x8*)&As[cof + afo[i]];
#pragma unroll
    for (int j = 0; j < 4; ++j) bfr[j] = *(const bf16x8*)&Bs[cof + bfo[j]];
#pragma unroll
    for (int i = 0; i < 4; ++i)
#pragma unroll
      for (int j = 0; j < 4; ++j)
        acc[i][j] = __builtin_amdgcn_mfma_f32_16x16x32_bf16(af[i], bfr[j], acc[i][j], 0, 0, 0);
    __syncthreads();   // after compute: drains next-tile DMA, gates cur overwrite
    cur ^= 1;
  }

  // epilogue: D[row=q*4+r][col=l16] per 16x16 tile (verified layout) -> fp32 partials
  float* Pz = P + (size_t)kz * M * Nc;
#pragma unroll
  for (int i = 0; i < 4; ++i) {
    int rowb = m0 + wr + i * 16 + q * 4;
#pragma unroll
    for (int j = 0; j < 4; ++j) {
      int col = n0 + wc + j * 16 + l16;
#pragma unroll
      for (int r = 0; r < 4; ++r)
        Pz[(size_t)(rowb + r) * Nc + col] = acc[i][j][r];
    }
  }
}

// ---- split-K reduce + bias (+ReLU) (+bf16 cast) ----
template <int S, bool RELU, bool BF16OUT>
__global__ void reduce_split(const float* __restrict__ P, const float* __restrict__ bias,
                             void* __restrict__ outp, int M, int Nc) {
  const long MN4 = (long)M * Nc / 4;
  const int nc4 = Nc / 4;
  long i = (long)blockIdx.x * blockDim.x + threadIdx.x;
  long stride = (long)gridDim.x * blockDim.x;
  const float4* P4 = (const float4*)P;
  const float4* B4 = (const float4*)bias;
  for (; i < MN4; i += stride) {
    float4 v = P4[i];
#pragma unroll
    for (int s = 1; s < S; ++s) {
      float4 u = P4[s * MN4 + i];
      v.x += u.x; v.y += u.y; v.z += u.z; v.w += u.w;
    }
    float4 b = B4[i % nc4];
    v.x += b.x; v.y += b.y; v.z += b.z; v.w += b.w;
    if (RELU) {
      v.x = fmaxf(v.x, 0.f); v.y = fmaxf(v.y, 0.f);
      v.z = fmaxf(v.z, 0.f); v.w = fmaxf(v.w, 0.f);
    }
    if (BF16OUT) {
      ushort4 u; u.x = f2bf(v.x); u.y = f2bf(v.y); u.z = f2bf(v.z); u.w = f2bf(v.w);
      ((ushort4*)outp)[i] = u;
    } else {
      ((float4*)outp)[i] = v;
    }
  }
}

// ---- per-row loss, reading GEMM3's 4 split-K partial slices + bias directly ----
__global__ void loss_row(const float* __restrict__ P, const float* __restrict__ bh,
                         const int* __restrict__ labels, const float* __restrict__ tgts,
                         float* __restrict__ nll_v, float* __restrict__ vc_v,
                         float* __restrict__ sl1_v) {
  int r = blockIdx.x;
  int l = threadIdx.x;
  const size_t SL = (size_t)RT * NH;
  const float* p0 = P + (size_t)r * NH;
  float v1 = p0[l] + p0[SL + l] + p0[2 * SL + l] + p0[3 * SL + l] + bh[l];
  float v2 = -3.4e38f;
  if (l < CC - 64) {
    int c = 64 + l;
    v2 = p0[c] + p0[SL + c] + p0[2 * SL + c] + p0[3 * SL + c] + bh[c];
  }
  float m = fmaxf(v1, v2);
#pragma unroll
  for (int o = 32; o; o >>= 1) m = fmaxf(m, __shfl_xor(m, o));
  float e = __expf(v1 - m) + ((l < CC - 64) ? __expf(v2 - m) : 0.0f);
#pragma unroll
  for (int o = 32; o; o >>= 1) e += __shfl_xor(e, o);
  if (l == 0) {
    float lse = m + __logf(e);
    int lab = labels[r];
    int sl = lab < 0 ? 0 : (lab > CC - 1 ? CC - 1 : lab);
    float valid = (lab >= 0) ? 1.0f : 0.0f;
    float logit = p0[sl] + p0[SL + sl] + p0[2 * SL + sl] + p0[3 * SL + sl] + bh[sl];
    nll_v[r] = (lse - logit) * valid;
    vc_v[r] = valid;
    float s = 0.0f;
#pragma unroll
    for (int d = 0; d < 4; ++d) {
      int c = CC + sl * 4 + d;
      float pd = p0[c] + p0[SL + c] + p0[2 * SL + c] + p0[3 * SL + c] + bh[c];
      float ad = fabsf(pd - tgts[r * 4 + d]);
      s += (ad < BETA) ? 0.5f * ad * ad / BETA : ad - 0.5f * BETA;
    }
    sl1_v[r] = (lab > 0) ? s : 0.0f;
  }
}

// ---- deterministic final reduce ----
__global__ void reduce_final(const float* __restrict__ nll_v, const float* __restrict__ vc_v,
                             const float* __restrict__ sl1_v, float* __restrict__ out) {
  __shared__ float s1[256], s2[256], s3[256];
  int t = threadIdx.x;
  float a = 0, b = 0, c = 0;
  for (int i = t; i < RT; i += 256) { a += nll_v[i]; b += vc_v[i]; c += sl1_v[i]; }
  s1[t] = a; s2[t] = b; s3[t] = c;
  __syncthreads();
  for (int o = 128; o; o >>= 1) {
    if (t < o) { s1[t] += s1[t + o]; s2[t] += s2[t + o]; s3[t] += s3[t + o]; }
    __syncthreads();
  }
  if (t == 0) {
    out[0] = s1[0] / fmaxf(s2[0], 1.0f);
    out[1] = s3[0] / (float)RT;
  }
}

extern "C" void kernel_launch(void* const* d_in, const int* in_sizes, int n_in,
                              void* d_out, int out_size, void* d_ws, size_t ws_size,
                              hipStream_t stream) {
  const float* proposals = (const float*)d_in[0];
  const float* gt_boxes  = (const float*)d_in[1];
  const float* features  = (const float*)d_in[2];
  const float* W1   = (const float*)d_in[3];
  const float* b1   = (const float*)d_in[4];
  const float* W2   = (const float*)d_in[5];
  const float* b2   = (const float*)d_in[6];
  const float* Wcls = (const float*)d_in[7];
  const float* bcls = (const float*)d_in[8];
  const float* Wbox = (const float*)d_in[9];
  const float* bbox = (const float*)d_in[10];
  const int* gt_labels = (const int*)d_in[11];
  float* out = (float*)d_out;

  char* ws = (char*)d_ws;
  unsigned short* W1t = (unsigned short*)(ws + O_W1T);
  unsigned short* W2t = (unsigned short*)(ws + O_W2T);
  unsigned short* Wh  = (unsigned short*)(ws + O_WH);
  float* bh           = (float*)(ws + O_BH);
  unsigned short* x1  = (unsigned short*)(ws + O_X1);
  unsigned short* x2  = (unsigned short*)(ws + O_X2);
  int* labels         = (int*)(ws + O_LAB);
  float* tgts         = (float*)(ws + O_TGT);
  float* nll_v        = (float*)(ws + O_NLL);
  float* vc_v         = (float*)(ws + O_VC);
  float* sl1_v        = (float*)(ws + O_SL1);
  float* part         = (float*)(ws + O_PART);
  unsigned short* feat_bf = (unsigned short*)(ws + O_FEAT);

  // 1. prep: feature convert + weight transposes + head init + matcher
  prep<<<NB_PREP, 256, 0, stream>>>(features, feat_bf, W1, W2, Wcls, Wbox,
                                    bcls, bbox, proposals, gt_boxes, gt_labels,
                                    W1t, W2t, Wh, bh, labels, tgts);

  // 2. GEMM1: split-4, 1056 blocks (4 blocks/CU resident)
  gemm_db<<<dim3(REPD / 128, RT / 128, 4), 256, 0, stream>>>(feat_bf, W1t, part,
                                                             RT, REPD, FEATD, FEATD / 4);
  reduce_split<4, true, true><<<1056, 256, 0, stream>>>(part, b1, x1, RT, REPD);

  // 3. GEMM2: split-4 (nk=8), 1056 blocks
  gemm_db<<<dim3(REPD / 128, RT / 128, 4), 256, 0, stream>>>(x1, W2t, part,
                                                             RT, REPD, REPD, REPD / 4);
  reduce_split<4, true, true><<<1056, 256, 0, stream>>>(part, b2, x2, RT, REPD);

  // 4. GEMM3: split-4, 528 blocks; partials consumed directly by loss_row
  gemm_db<<<dim3(NH / 128, RT / 128, 4), 256, 0, stream>>>(x2, Wh, part,
                                                           RT, NH, REPD, REPD / 4);

  // 5. losses
  loss_row<<<RT, 64, 0, stream>>>(part, bh, labels, tgts, nll_v, vc_v, sl1_v);
  reduce_final<<<1, 256, 0, stream>>>(nll_v, vc_v, sl1_v, out);
}

// Round 5
// 500.816 us; speedup vs baseline: 1.4020x; 1.2531x over previous
//
#include <hip/hip_runtime.h>
#include <cstdint>
#include <cstddef>

// ---- problem constants ----
#define BQ   8
#define NP   512
#define GQ   16
#define PP   528      // NP + GQ
#define RT   4224     // BQ * PP
#define CC   91
#define FEATD 12544
#define REPD 1024
#define NH   512      // padded head output cols (455 used: 91 cls + 364 box)
#define NHU  455
#define BETA (1.0f/9.0f)
#define WSC  64.0f    // fp8 weight pre-scale (exact pow2; undone in reduce/loss)

typedef float f32x4 __attribute__((ext_vector_type(4)));

__device__ __forceinline__ unsigned short f2bf(float f) {
  unsigned int x = __float_as_uint(f);
  unsigned int r = (x + 0x7fffu + ((x >> 16) & 1u)) >> 16;
  return (unsigned short)r;
}
__device__ __forceinline__ float bf2f(unsigned short u) {
  return __uint_as_float((unsigned int)u << 16);
}
__device__ __forceinline__ unsigned char f2fp8(float f) {
  return (unsigned char)(__builtin_amdgcn_cvt_pk_fp8_f32(f, 0.0f, 0, false) & 0xff);
}

// async global->LDS DMA, 16 B per lane; HW writes lane L to base + L*16.
__device__ __forceinline__ void ld_lds16(const void* g, void* l) {
  __builtin_amdgcn_global_load_lds(
      (const __attribute__((address_space(1))) void*)g,
      (__attribute__((address_space(3))) void*)l, 16, 0, 0);
}

// ---- workspace layout (bytes); total ~107 MB (ws >= 230.6 MB proven R2) ----
constexpr size_t O_W1T = 0;
constexpr size_t SZ_W1T = (size_t)FEATD * REPD;             // W1^T fp8 [1024][12544]
constexpr size_t O_W2T = O_W1T + SZ_W1T;
constexpr size_t SZ_W2T = (size_t)REPD * REPD;              // W2^T fp8
constexpr size_t O_WH  = O_W2T + SZ_W2T;
constexpr size_t SZ_WH = (size_t)NH * REPD;                 // [Wcls|Wbox]^T fp8
constexpr size_t O_BH  = O_WH + SZ_WH;
constexpr size_t SZ_BH = (size_t)NH * 4;
constexpr size_t O_X1  = O_BH + SZ_BH;
constexpr size_t SZ_X1 = (size_t)RT * REPD;                 // x1 fp8
constexpr size_t O_X2  = O_X1 + SZ_X1;                      // x2 fp8
constexpr size_t O_LAB = O_X2 + SZ_X1;
constexpr size_t O_TGT = O_LAB + (size_t)RT * 4;
constexpr size_t O_NLL = O_TGT + (size_t)RT * 16;
constexpr size_t O_VC  = O_NLL + (size_t)RT * 4;
constexpr size_t O_SL1 = O_VC + (size_t)RT * 4;
constexpr size_t O_PART = ((O_SL1 + (size_t)RT * 4) + 255) & ~(size_t)255;
constexpr size_t SZ_PART = (size_t)4 * RT * REPD * 2;       // bf16 partials, 34.6 MB max
constexpr size_t O_F8 = O_PART + SZ_PART;                   // fp8 features, 53 MB

// ---- prep: feature fp8-convert + weight transpose-convert(x64) + head + matcher ----
__device__ __forceinline__ void t32(const float* __restrict__ in, unsigned char* __restrict__ out,
                                    int K, int N, int row_off, int out_ld,
                                    int bx, int by, int t, float (*tile)[33]) {
  int tx = t & 31, ty = t >> 5;
  int n0 = bx * 32, k0 = by * 32;
#pragma unroll
  for (int i = 0; i < 4; ++i) {
    int k = k0 + ty + i * 8, n = n0 + tx;
    if (k < K && n < N) tile[ty + i * 8][tx] = in[(size_t)k * N + n];
  }
  __syncthreads();
#pragma unroll
  for (int i = 0; i < 4; ++i) {
    int n = n0 + ty + i * 8, k = k0 + tx;
    if (n < N && k < K) out[(size_t)(n + row_off) * out_ld + k] = f2fp8(tile[tx][ty + i * 8] * WSC);
  }
}

#define NB_CV ((RT * FEATD / 4) / 256)   // 51744
#define NB_W1 ((REPD/32)*(FEATD/32))     // 12544
#define NB_W2 ((REPD/32)*(REPD/32))      // 1024
#define NB_WC (3*(REPD/32))              // 96
#define NB_WB (12*(REPD/32))             // 384
#define NB_HI 230
#define NB_MT 17
#define NB_PREP (NB_CV+NB_W1+NB_W2+NB_WC+NB_WB+NB_HI+NB_MT)

__global__ void prep(const float* __restrict__ feat, unsigned int* __restrict__ feat8,
                     const float* __restrict__ W1, const float* __restrict__ W2,
                     const float* __restrict__ Wcls, const float* __restrict__ Wbox,
                     const float* __restrict__ bcls, const float* __restrict__ bbox,
                     const float* __restrict__ proposals, const float* __restrict__ gt_boxes,
                     const int* __restrict__ gt_labels,
                     unsigned char* __restrict__ W1t, unsigned char* __restrict__ W2t,
                     unsigned char* __restrict__ Wh, float* __restrict__ bh,
                     int* __restrict__ labels, float* __restrict__ tgts) {
  __shared__ float tile[32][33];
  int b = blockIdx.x, t = threadIdx.x;
  if (b < NB_CV) {
    long i = (long)b * 256 + t;
    float4 f = ((const float4*)feat)[i];
    unsigned int r = (unsigned int)__builtin_amdgcn_cvt_pk_fp8_f32(f.x, f.y, 0, false);
    r = (unsigned int)__builtin_amdgcn_cvt_pk_fp8_f32(f.z, f.w, (int)r, true);
    feat8[i] = r;
    return;
  }
  b -= NB_CV;
  if (b < NB_W1) { t32(W1, W1t, FEATD, REPD, 0, FEATD, b % (REPD/32), b / (REPD/32), t, tile); return; }
  b -= NB_W1;
  if (b < NB_W2) { t32(W2, W2t, REPD, REPD, 0, REPD, b % 32, b / 32, t, tile); return; }
  b -= NB_W2;
  if (b < NB_WC) { t32(Wcls, Wh, REPD, CC, 0, REPD, b % 3, b / 3, t, tile); return; }
  b -= NB_WC;
  if (b < NB_WB) { t32(Wbox, Wh, REPD, 4 * CC, CC, REPD, b % 12, b / 12, t, tile); return; }
  b -= NB_WB;
  if (b < NB_HI) {
    int idx = b * 256 + t;
    const int npad = (NH - NHU) * REPD;   // 58368 bytes of fp8 zero
    if (idx < npad) Wh[(size_t)NHU * REPD + idx] = 0;
    else {
      int i2 = idx - npad;
      if (i2 < NH) bh[i2] = (i2 < CC) ? bcls[i2] : (i2 < NHU ? bbox[i2 - CC] : 0.0f);
    }
    return;
  }
  b -= NB_HI;
  // ---- matcher + encode (exact fp32) ----
  int r = b * 256 + t;
  if (r >= RT) return;
  int bi_ = r / PP, p = r % PP;
  float x0, y0, x1, y1;
  if (p < NP) {
    const float* qq = proposals + ((size_t)bi_ * NP + p) * 4;
    x0 = qq[0]; y0 = qq[1]; x1 = qq[2]; y1 = qq[3];
  } else {
    const float* qq = gt_boxes + ((size_t)bi_ * GQ + (p - NP)) * 4;
    x0 = qq[0]; y0 = qq[1]; x1 = qq[2]; y1 = qq[3];
  }
  float ap = (x1 - x0) * (y1 - y0);
  float best = -1.0f; int bg = 0;
#pragma unroll
  for (int g = 0; g < GQ; ++g) {
    const float* gb = gt_boxes + ((size_t)bi_ * GQ + g) * 4;
    float gx0 = gb[0], gy0 = gb[1], gx1 = gb[2], gy1 = gb[3];
    float ag = (gx1 - gx0) * (gy1 - gy0);
    float iw = fmaxf(fminf(gx1, x1) - fmaxf(gx0, x0), 0.0f);
    float ih = fmaxf(fminf(gy1, y1) - fmaxf(gy0, y0), 0.0f);
    float inter = iw * ih;
    float iou = inter / (ag + ap - inter);
    if (iou > best) { best = iou; bg = g; }   // strict > keeps first max (jnp.argmax)
  }
  int lab = gt_labels[bi_ * GQ + bg];
  if (best < 0.5f) lab = 0;    // FG==BG==0.5 -> ignore band empty
  labels[r] = lab;
  const float* gb = gt_boxes + ((size_t)bi_ * GQ + bg) * 4;
  float ew = x1 - x0, eh = y1 - y0;
  float ex = x0 + 0.5f * ew, ey = y0 + 0.5f * eh;
  float gw = gb[2] - gb[0], gh = gb[3] - gb[1];
  float gx = gb[0] + 0.5f * gw, gy = gb[1] + 0.5f * gh;
  tgts[r * 4 + 0] = 10.0f * (gx - ex) / ew;
  tgts[r * 4 + 1] = 10.0f * (gy - ey) / eh;
  tgts[r * 4 + 2] = 5.0f * logf(gw / ew);
  tgts[r * 4 + 3] = 5.0f * logf(gh / eh);
}

// ---- fp8 MFMA GEMM: 128x128 tile, BK=64, single-buffer 2-barrier (R2-proven) ----
// A,Bt fp8; D = A*Bt^T accumulated fp32, stored as bf16 split-K partials.
// XCD pair-mapping: xcd = g&7; pair p = pi*8+xcd -> all 8 n-blocks sharing an
// A-slice run on ONE XCD (A fetched once from HBM; B kz-slice L2-resident).
// LDS: 64B rows; fetch chunk (L&3)^((L>>3)&3); fragment chunk (kk*2+(q>>1))^((l16>>1)&3)
// -> theoretical-minimum bank spread on both sides.
__global__ __launch_bounds__(256, 4)
void gemm_f8(const unsigned char* __restrict__ A, const unsigned char* __restrict__ Bt,
             unsigned short* __restrict__ P, int M, int Nc, int K, int Kspl,
             int n_nblk, int n_my, int npairs) {
  __shared__ unsigned char As[128 * 64];
  __shared__ unsigned char Bs[128 * 64];

  const int g = blockIdx.x;
  const int xcd = g & 7;
  const int kix = g >> 3;
  const int n  = kix % n_nblk;
  const int pi = kix / n_nblk;
  const int p  = pi * 8 + xcd;
  if (p >= npairs) return;                 // uniform dummy exit, before any barrier
  const int y  = p % n_my;
  const int kz = p / n_my;
  const int m0 = y * 128, n0 = n * 128;

  const int tid = threadIdx.x;
  const int w = tid >> 6, L = tid & 63;
  const int q = L >> 4, l16 = L & 15;
  const int wr = (w >> 1) * 64, wc = (w & 1) * 64;
  const size_t kbase = (size_t)kz * Kspl;

  // DMA: seg = 16 rows x 64 B = 1 KB; wave w owns A segs {2w,2w+1}, B segs {2w,2w+1}
  const int lrow = L >> 2;                          // row within seg
  const int loff = ((L & 3) ^ ((L >> 3) & 3)) * 16; // swizzled 16B chunk in 64B window
  const int sg = 2 * w;
  const unsigned char* gA0 = A  + (size_t)(m0 + sg * 16 + lrow) * K + kbase + loff;
  const unsigned char* gA1 = A  + (size_t)(m0 + (sg + 1) * 16 + lrow) * K + kbase + loff;
  const unsigned char* gB0 = Bt + (size_t)(n0 + sg * 16 + lrow) * K + kbase + loff;
  const unsigned char* gB1 = Bt + (size_t)(n0 + (sg + 1) * 16 + lrow) * K + kbase + loff;
  unsigned char* lA0 = &As[sg * 1024];
  unsigned char* lA1 = &As[(sg + 1) * 1024];
  unsigned char* lB0 = &Bs[sg * 1024];
  unsigned char* lB1 = &Bs[(sg + 1) * 1024];

  // fragment offsets (swizzle folded): row base + chunk(kk,q) + 8B half(q)
  const int s2f = (l16 >> 1) & 3;
  const int fo0 = (((q >> 1) ^ s2f) * 16) + (q & 1) * 8;        // kk=0
  const int fo1 = (((2 + (q >> 1)) ^ s2f) * 16) + (q & 1) * 8;  // kk=1
  int ao[4], bo[4];
#pragma unroll
  for (int i = 0; i < 4; ++i) {
    ao[i] = (wr + i * 16 + l16) * 64;
    bo[i] = (wc + i * 16 + l16) * 64;
  }

  f32x4 acc[4][4] = {};
  const int nk = Kspl >> 6;
  for (int kb = 0; kb < nk; ++kb) {
    const int ko = kb * 64;
    ld_lds16(gA0 + ko, lA0);
    ld_lds16(gA1 + ko, lA1);
    ld_lds16(gB0 + ko, lB0);
    ld_lds16(gB1 + ko, lB1);
    __syncthreads();   // vmcnt drain + barrier: tile staged
    long a0[4], a1[4], b0[4], b1[4];
#pragma unroll
    for (int i = 0; i < 4; ++i) {
      a0[i] = *(const long*)&As[ao[i] + fo0];
      a1[i] = *(const long*)&As[ao[i] + fo1];
    }
#pragma unroll
    for (int j = 0; j < 4; ++j) {
      b0[j] = *(const long*)&Bs[bo[j] + fo0];
      b1[j] = *(const long*)&Bs[bo[j] + fo1];
    }
#pragma unroll
    for (int i = 0; i < 4; ++i)
#pragma unroll
      for (int j = 0; j < 4; ++j) {
        acc[i][j] = __builtin_amdgcn_mfma_f32_16x16x32_fp8_fp8(a0[i], b0[j], acc[i][j], 0, 0, 0);
        acc[i][j] = __builtin_amdgcn_mfma_f32_16x16x32_fp8_fp8(a1[i], b1[j], acc[i][j], 0, 0, 0);
      }
    __syncthreads();   // protect LDS from next iteration's DMA
  }

  // epilogue: D[row=q*4+r][col=l16] (verified, dtype-independent) -> bf16 partials
  unsigned short* Pz = P + (size_t)kz * M * Nc;
#pragma unroll
  for (int i = 0; i < 4; ++i) {
    int rowb = m0 + wr + i * 16 + q * 4;
#pragma unroll
    for (int j = 0; j < 4; ++j) {
      int col = n0 + wc + j * 16 + l16;
#pragma unroll
      for (int r = 0; r < 4; ++r)
        Pz[(size_t)(rowb + r) * Nc + col] = f2bf(acc[i][j][r]);
    }
  }
}

// ---- split-K reduce (bf16 partials) + 1/WSC + bias + ReLU -> fp8 out ----
template <int S>
__global__ void reduce_fp8k(const unsigned short* __restrict__ P, const float* __restrict__ bias,
                            unsigned int* __restrict__ outp, long MN4, int nc4) {
  long i = (long)blockIdx.x * blockDim.x + threadIdx.x;
  long stride = (long)gridDim.x * blockDim.x;
  const ushort4* P4 = (const ushort4*)P;
  const float4* B4 = (const float4*)bias;
  for (; i < MN4; i += stride) {
    float vx = 0, vy = 0, vz = 0, vw = 0;
#pragma unroll
    for (int s = 0; s < S; ++s) {
      ushort4 u = P4[s * MN4 + i];
      vx += bf2f(u.x); vy += bf2f(u.y); vz += bf2f(u.z); vw += bf2f(u.w);
    }
    float4 b = B4[i % nc4];
    vx = fmaxf(vx * (1.0f / WSC) + b.x, 0.0f);
    vy = fmaxf(vy * (1.0f / WSC) + b.y, 0.0f);
    vz = fmaxf(vz * (1.0f / WSC) + b.z, 0.0f);
    vw = fmaxf(vw * (1.0f / WSC) + b.w, 0.0f);
    unsigned int r = (unsigned int)__builtin_amdgcn_cvt_pk_fp8_f32(vx, vy, 0, false);
    r = (unsigned int)__builtin_amdgcn_cvt_pk_fp8_f32(vz, vw, (int)r, true);
    outp[i] = r;
  }
}

// ---- per-row loss, reading GEMM3's 4 bf16 split-K slices + bias directly ----
__global__ void loss_row(const unsigned short* __restrict__ P, const float* __restrict__ bh,
                         const int* __restrict__ labels, const float* __restrict__ tgts,
                         float* __restrict__ nll_v, float* __restrict__ vc_v,
                         float* __restrict__ sl1_v) {
  int r = blockIdx.x;
  int l = threadIdx.x;
  const size_t SL = (size_t)RT * NH;
  const unsigned short* p0 = P + (size_t)r * NH;
#define COLV(c) ((bf2f(p0[(c)]) + bf2f(p0[SL + (c)]) + bf2f(p0[2 * SL + (c)]) + \
                  bf2f(p0[3 * SL + (c)])) * (1.0f / WSC) + bh[(c)])
  float v1 = COLV(l);
  float v2 = (l < CC - 64) ? COLV(64 + l) : -3.4e38f;
  float m = fmaxf(v1, v2);
#pragma unroll
  for (int o = 32; o; o >>= 1) m = fmaxf(m, __shfl_xor(m, o));
  float e = __expf(v1 - m) + ((l < CC - 64) ? __expf(v2 - m) : 0.0f);
#pragma unroll
  for (int o = 32; o; o >>= 1) e += __shfl_xor(e, o);
  if (l == 0) {
    float lse = m + __logf(e);
    int lab = labels[r];
    int sl = lab < 0 ? 0 : (lab > CC - 1 ? CC - 1 : lab);
    float valid = (lab >= 0) ? 1.0f : 0.0f;
    nll_v[r] = (lse - COLV(sl)) * valid;
    vc_v[r] = valid;
    float s = 0.0f;
#pragma unroll
    for (int d = 0; d < 4; ++d) {
      float pd = COLV(CC + sl * 4 + d);
      float ad = fabsf(pd - tgts[r * 4 + d]);
      s += (ad < BETA) ? 0.5f * ad * ad / BETA : ad - 0.5f * BETA;
    }
    sl1_v[r] = (lab > 0) ? s : 0.0f;
  }
#undef COLV
}

// ---- deterministic final reduce ----
__global__ void reduce_final(const float* __restrict__ nll_v, const float* __restrict__ vc_v,
                             const float* __restrict__ sl1_v, float* __restrict__ out) {
  __shared__ float s1[256], s2[256], s3[256];
  int t = threadIdx.x;
  float a = 0, b = 0, c = 0;
  for (int i = t; i < RT; i += 256) { a += nll_v[i]; b += vc_v[i]; c += sl1_v[i]; }
  s1[t] = a; s2[t] = b; s3[t] = c;
  __syncthreads();
  for (int o = 128; o; o >>= 1) {
    if (t < o) { s1[t] += s1[t + o]; s2[t] += s2[t + o]; s3[t] += s3[t + o]; }
    __syncthreads();
  }
  if (t == 0) {
    out[0] = s1[0] / fmaxf(s2[0], 1.0f);
    out[1] = s3[0] / (float)RT;
  }
}

extern "C" void kernel_launch(void* const* d_in, const int* in_sizes, int n_in,
                              void* d_out, int out_size, void* d_ws, size_t ws_size,
                              hipStream_t stream) {
  const float* proposals = (const float*)d_in[0];
  const float* gt_boxes  = (const float*)d_in[1];
  const float* features  = (const float*)d_in[2];
  const float* W1   = (const float*)d_in[3];
  const float* b1   = (const float*)d_in[4];
  const float* W2   = (const float*)d_in[5];
  const float* b2   = (const float*)d_in[6];
  const float* Wcls = (const float*)d_in[7];
  const float* bcls = (const float*)d_in[8];
  const float* Wbox = (const float*)d_in[9];
  const float* bbox = (const float*)d_in[10];
  const int* gt_labels = (const int*)d_in[11];
  float* out = (float*)d_out;

  char* ws = (char*)d_ws;
  unsigned char* W1t = (unsigned char*)(ws + O_W1T);
  unsigned char* W2t = (unsigned char*)(ws + O_W2T);
  unsigned char* Wh  = (unsigned char*)(ws + O_WH);
  float* bh          = (float*)(ws + O_BH);
  unsigned char* x1  = (unsigned char*)(ws + O_X1);
  unsigned char* x2  = (unsigned char*)(ws + O_X2);
  int* labels        = (int*)(ws + O_LAB);
  float* tgts        = (float*)(ws + O_TGT);
  float* nll_v       = (float*)(ws + O_NLL);
  float* vc_v        = (float*)(ws + O_VC);
  float* sl1_v       = (float*)(ws + O_SL1);
  unsigned short* part = (unsigned short*)(ws + O_PART);
  unsigned char* feat8 = (unsigned char*)(ws + O_F8);

  // 1. prep: feature fp8 convert + weight transpose-convert(x64) + head + matcher
  prep<<<NB_PREP, 256, 0, stream>>>(features, (unsigned int*)feat8, W1, W2, Wcls, Wbox,
                                    bcls, bbox, proposals, gt_boxes, gt_labels,
                                    W1t, W2t, Wh, bh, labels, tgts);

  // 2. GEMM1: split-4, pairs=(y,kz)=132, 8 n-blocks -> grid 8*8*17=1088
  gemm_f8<<<1088, 256, 0, stream>>>(feat8, W1t, part, RT, REPD, FEATD, FEATD / 4,
                                    8, 33, 132);
  reduce_fp8k<4><<<2048, 256, 0, stream>>>(part, b1, (unsigned int*)x1,
                                           (long)RT * REPD / 4, REPD / 4);

  // 3. GEMM2: split-2, pairs=66 -> grid 8*8*9=576
  gemm_f8<<<576, 256, 0, stream>>>(x1, W2t, part, RT, REPD, REPD, REPD / 2,
                                   8, 33, 66);
  reduce_fp8k<2><<<2048, 256, 0, stream>>>(part, b2, (unsigned int*)x2,
                                           (long)RT * REPD / 4, REPD / 4);

  // 4. GEMM3: split-4, Nc=512 (4 n-blocks), pairs=132 -> grid 8*4*17=544
  gemm_f8<<<544, 256, 0, stream>>>(x2, Wh, part, RT, NH, REPD, REPD / 4,
                                   4, 33, 132);

  // 5. losses (loss_row folds GEMM3's 4-slice reduce + bias + 1/WSC)
  loss_row<<<RT, 64, 0, stream>>>(part, bh, labels, tgts, nll_v, vc_v, sl1_v);
  reduce_final<<<1, 256, 0, stream>>>(nll_v, vc_v, sl1_v, out);
}